// Round 3
// baseline (16483.434 us; speedup 1.0000x reference)
//
#include <hip/hip_runtime.h>
#include <hip/hip_bf16.h>
#include <math.h>

// ---------------------------------------------------------------------------
// AttentiveFP forward, MI355X. Round 3: adaptive workspace (~224MB fixed),
// bf16 hidden state, fp32 compute, chunked GRUs, fused epilogues.
// ---------------------------------------------------------------------------

typedef __hip_bfloat16 bf16;
__device__ __forceinline__ float b2f(bf16 v) { return __bfloat162float(v); }
__device__ __forceinline__ bf16 f2b(float v) { return __float2bfloat16(v); }

#define NEGS 0.01f

__device__ __forceinline__ unsigned fkey(float f) {
    unsigned u = __float_as_uint(f);
    return (u & 0x80000000u) ? ~u : (u | 0x80000000u);
}
__device__ __forceinline__ float funkey(unsigned k) {
    return (k & 0x80000000u) ? __uint_as_float(k ^ 0x80000000u) : __uint_as_float(~k);
}
#define KEY_NEG_INF 0x007FFFFFu

// ---------------- utility kernels ----------------
__global__ void fill_f32(float* p, float v, size_t n) {
    size_t i = (size_t)blockIdx.x * 256 + threadIdx.x;
    if (i < n) p[i] = v;
}
__global__ void fill_u32(unsigned* p, unsigned v, int n) {
    int i = blockIdx.x * 256 + threadIdx.x;
    if (i < n) p[i] = v;
}
__global__ void setbias_k(float* dst, const float* b, int M) {
    int m = blockIdx.x;
    if (m < M) dst[(size_t)m * 256 + threadIdx.x] = b ? b[threadIdx.x] : 0.f;
}
__global__ void relu_inplace(float* p, size_t n) {
    size_t i = (size_t)blockIdx.x * 256 + threadIdx.x;
    if (i < n) p[i] = fmaxf(p[i], 0.f);
}
// v[col] = sum_row W[row*Jout+col]*a[row]
__global__ void matvecT_k(const float* W, const float* a, float* v, int K, int Jout) {
    int j = blockIdx.x * 256 + threadIdx.x;
    if (j >= Jout) return;
    float s = 0.f;
    for (int k = 0; k < K; k++) s += W[(size_t)k * Jout + j] * a[k];
    v[j] = s;
}
__global__ void edge_add_lrelu(float* elog, const float* r, const int* dsti, int E) {
    int i = blockIdx.x * 256 + threadIdx.x;
    if (i < E) {
        float v = elog[i] + r[dsti[i]];
        elog[i] = v > 0.f ? v : NEGS * v;
    }
}
__global__ void pair_logit(float* elog, const float* s, const float* d,
                           const int* srci, const int* dsti, int E) {
    int i = blockIdx.x * 256 + threadIdx.x;
    if (i < E) {
        float v = s[srci[i]] + d[dsti[i]];
        elog[i] = v > 0.f ? v : NEGS * v;
    }
}
__global__ void node_logit(float* nlog, const float* asrc, const float* wg,
                           const int* batch, int N) {
    int i = blockIdx.x * 256 + threadIdx.x;
    if (i < N) {
        float v = asrc[i] + wg[batch[i]];
        nlog[i] = v > 0.f ? v : NEGS * v;
    }
}
__global__ void seg_max_k(const float* logit, const int* idx, unsigned* key, int n) {
    int i = blockIdx.x * 256 + threadIdx.x;
    if (i < n) atomicMax(&key[idx[i]], fkey(logit[i]));
}
__global__ void seg_exp_k(const float* logit, const int* idx, const unsigned* key,
                          float* ex, float* sum, int n) {
    int i = blockIdx.x * 256 + threadIdx.x;
    if (i < n) {
        float e = expf(logit[i] - funkey(key[idx[i]]));
        ex[i] = e;
        atomicAdd(&sum[idx[i]], e);
    }
}
__global__ void seg_div_k(const float* ex, const int* idx, const float* sum,
                          float* a, int n) {
    int i = blockIdx.x * 256 + threadIdx.x;
    if (i < n) a[i] = ex[i] / (sum[idx[i]] + 1e-16f);
}
// dst[gdst[r],c] += b2f(V[(gsrc?gsrc[r]:r),c]) * (sc?sc[r]:1)   (V is bf16)
__global__ void scatter_rows_b(const bf16* V, const int* gsrc, const float* sc,
                               const int* gdst, float* dst, int M) {
    int r = blockIdx.x;
    if (r >= M) return;
    int c = threadIdx.x;
    int vr = gsrc ? gsrc[r] : r;
    float v = b2f(V[(size_t)vr * 256 + c]);
    if (sc) v *= sc[r];
    atomicAdd(&dst[(size_t)gdst[r] * 256 + c], v);
}
// per-row dot (bf16 X) with up to 2 fp32 vectors
__global__ void rowdot2_b(const bf16* X, const float* v1, const float* v2,
                          float* o1, float* o2, int M) {
    int r = blockIdx.x * 4 + (threadIdx.x >> 6);
    int lane = threadIdx.x & 63;
    if (r >= M) return;
    const bf16* row = X + (size_t)r * 256 + lane * 4;
    float p1 = 0.f, p2 = 0.f;
#pragma unroll
    for (int q = 0; q < 4; q++) {
        float xv = b2f(row[q]);
        p1 += xv * v1[lane * 4 + q];
        if (v2) p2 += xv * v2[lane * 4 + q];
    }
    for (int off = 32; off; off >>= 1) {
        p1 += __shfl_down(p1, off);
        if (v2) p2 += __shfl_down(p2, off);
    }
    if (lane == 0) {
        o1[r] = p1;
        if (v2) o2[r] = p2;
    }
}
__global__ void rowdot_f(const float* X, const float* v1, float* o1, int M) {
    int r = blockIdx.x * 4 + (threadIdx.x >> 6);
    int lane = threadIdx.x & 63;
    if (r >= M) return;
    float4 a = ((const float4*)(X + (size_t)r * 256))[lane];
    float4 b = ((const float4*)v1)[lane];
    float p1 = a.x * b.x + a.y * b.y + a.z * b.z + a.w * b.w;
    for (int off = 32; off; off >>= 1) p1 += __shfl_down(p1, off);
    if (lane == 0) o1[r] = p1;
}
// GRU combine; state bf16 (HB=1) or fp32
template <bool HB>
__global__ void gru_combine_k(const float* S, const float* hn, float* hf, bf16* hb, int M) {
    int m = blockIdx.x;
    if (m >= M) return;
    int c = threadIdx.x;
    float sr = S[(size_t)m * 768 + c];
    float sz = S[(size_t)m * 768 + 256 + c];
    float sn = S[(size_t)m * 768 + 512 + c];
    float hnv = hn[(size_t)m * 256 + c];
    float r = 1.f / (1.f + expf(-sr));
    float z = 1.f / (1.f + expf(-sz));
    float nv = tanhf(sn - hnv + r * hnv);
    float hv = HB ? b2f(hb[(size_t)m * 256 + c]) : hf[(size_t)m * 256 + c];
    float o = fmaxf((1.f - z) * nv + z * hv, 0.f);
    if (HB) hb[(size_t)m * 256 + c] = f2b(o);
    else hf[(size_t)m * 256 + c] = o;
}
__global__ void fc4_k(const float* X, const float* w, const float* b, float* out, int G) {
    int g = blockIdx.x * 4 + (threadIdx.x >> 6);
    int lane = threadIdx.x & 63;
    if (g >= G) return;
    float2 xv = ((const float2*)(X + (size_t)g * 128))[lane];
    float2 wv = ((const float2*)w)[lane];
    float p = xv.x * wv.x + xv.y * wv.y;
    for (int off = 32; off; off >>= 1) p += __shfl_down(p, off);
    if (lane == 0) out[g] = p + b[0];
}

// ---------------- tiled GEMM: C = act(A @ W^T + b1 + b2) ----------------
// AK: 0 dense f32 Af(lda); 1 [bf16 Ab[gidx[m]] (256) | f32 X2f (16)] K=272;
//     2 [elu(f32 Af) (256) | bf16 Ab] K=512; 3 [elu(f32 Af) | f32 X2f] K=512;
//     4 dense bf16 Ab(lda)
// WK: 0 dense [Nout,K] ldK; 1 stacked W(ld256)/W2(ld256)
// ACT: 0 none, 1 lrelu, 3 silu; DOTV: row-dot epilogue; SCAT: scatter epilogue
// CB: store C as bf16
#define BM 64
#define BN 64
#define BK 16

template <int AK>
__device__ __forceinline__ float loadA(const float* Af, const bf16* Ab, int lda,
                                       const int* gidx, const float* X2f, int m, int k) {
    if (AK == 0) return Af[(size_t)m * lda + k];
    if (AK == 1) {
        if (k < 256) return b2f(Ab[(size_t)gidx[m] * 256 + k]);
        return X2f[(size_t)m * 16 + (k - 256)];
    }
    if (AK == 2) {
        if (k < 256) {
            float x = Af[(size_t)m * 256 + k];
            return x > 0.f ? x : expm1f(x);
        }
        return b2f(Ab[(size_t)m * 256 + (k - 256)]);
    }
    if (AK == 3) {
        if (k < 256) {
            float x = Af[(size_t)m * 256 + k];
            return x > 0.f ? x : expm1f(x);
        }
        return X2f[(size_t)m * 256 + (k - 256)];
    }
    return b2f(Ab[(size_t)m * lda + k]);  // AK==4
}
template <int WK>
__device__ __forceinline__ float loadW(const float* W, const float* W2, int n, int k, int K) {
    if (WK == 0) return W[(size_t)n * K + k];
    if (k < 256) return W[(size_t)n * 256 + k];
    return W2[(size_t)n * 256 + (k - 256)];
}

template <int AK, int WK, int ACT, bool DOTV, bool SCAT, bool CB>
__global__ __launch_bounds__(256) void gemm_k(
    int M, int K, int Nout,
    const float* Af, const bf16* Ab, int lda, const int* gidx, const float* X2f,
    const float* W, const float* W2, const float* b1, const float* b2,
    float* Cf, bf16* Cb, int ldc,
    const float* attv, float* dotout,
    const int* didx, const float* escale, float* scat) {
    __shared__ float As[BK][BM + 4];
    __shared__ float Ws[BK][BN + 4];
    int m0 = blockIdx.x * BM, n0 = blockIdx.y * BN;
    int tid = threadIdx.x;
    int tr = tid >> 4, tc = tid & 15;
    float acc[4][4] = {};
    for (int kc = 0; kc < K; kc += BK) {
        for (int l = tid; l < BM * BK; l += 256) {
            int row = l >> 4, kk = l & 15;
            int m = m0 + row, k = kc + kk;
            float v = 0.f;
            if (m < M && k < K) v = loadA<AK>(Af, Ab, lda, gidx, X2f, m, k);
            As[kk][row] = v;
        }
        for (int l = tid; l < BN * BK; l += 256) {
            int row = l >> 4, kk = l & 15;
            int n = n0 + row, k = kc + kk;
            float v = 0.f;
            if (n < Nout && k < K) v = loadW<WK>(W, W2, n, k, K);
            Ws[kk][row] = v;
        }
        __syncthreads();
#pragma unroll
        for (int kk = 0; kk < BK; kk++) {
            float a_r[4], w_r[4];
#pragma unroll
            for (int i = 0; i < 4; i++) a_r[i] = As[kk][tr * 4 + i];
#pragma unroll
            for (int j = 0; j < 4; j++) w_r[j] = Ws[kk][tc * 4 + j];
#pragma unroll
            for (int i = 0; i < 4; i++)
#pragma unroll
                for (int j = 0; j < 4; j++) acc[i][j] += a_r[i] * w_r[j];
        }
        __syncthreads();
    }
    float dotp[4] = {0.f, 0.f, 0.f, 0.f};
#pragma unroll
    for (int i = 0; i < 4; i++) {
        int m = m0 + tr * 4 + i;
        if (m >= M) continue;
#pragma unroll
        for (int j = 0; j < 4; j++) {
            int n = n0 + tc * 4 + j;
            if (n >= Nout) continue;
            float v = acc[i][j];
            if (b1) v += b1[n];
            if (b2) v += b2[n];
            if (ACT == 1) v = v > 0.f ? v : NEGS * v;
            if (ACT == 3) v = v / (1.f + expf(-v));
            if (DOTV) dotp[i] += v * attv[n];
            if (SCAT) {
                atomicAdd(&scat[(size_t)didx[m] * 256 + n], v * escale[m]);
            } else if (CB) {
                if (Cb) Cb[(size_t)m * ldc + n] = f2b(v);
            } else if (Cf) {
                Cf[(size_t)m * ldc + n] = v;
            }
        }
    }
    if (DOTV) {
#pragma unroll
        for (int i = 0; i < 4; i++) {
            float p = dotp[i];
            for (int off = 8; off; off >>= 1) p += __shfl_down(p, off, 16);
            int m = m0 + tr * 4 + i;
            if (tc == 0 && m < M) atomicAdd(&dotout[m], p);
        }
    }
}

template <int AK, int WK, int ACT, bool DOTV, bool SCAT, bool CB>
static void launch_gemm(hipStream_t s, int M, int K, int Nout,
                        const float* Af, const bf16* Ab, int lda, const int* gidx,
                        const float* X2f, const float* W, const float* W2,
                        const float* b1, const float* b2, float* Cf, bf16* Cb, int ldc,
                        const float* attv, float* dotout,
                        const int* didx, const float* escale, float* scat) {
    dim3 g((M + BM - 1) / BM, (Nout + BN - 1) / BN);
    gemm_k<AK, WK, ACT, DOTV, SCAT, CB><<<g, 256, 0, s>>>(
        M, K, Nout, Af, Ab, lda, gidx, X2f, W, W2, b1, b2, Cf, Cb, ldc,
        attv, dotout, didx, escale, scat);
}

static inline int cdiv(int a, int b) { return (a + b - 1) / b; }

extern "C" void kernel_launch(void* const* d_in, const int* in_sizes, int n_in,
                              void* d_out, int out_size, void* d_ws, size_t ws_size,
                              hipStream_t stream) {
    const float* x = (const float*)d_in[0];
    const float* edge_attr = (const float*)d_in[1];
    const float* mol_feats = (const float*)d_in[2];
    const float* lin1_w = (const float*)d_in[3];
    const float* lin1_b = (const float*)d_in[4];
    const float* gate_lin1_w = (const float*)d_in[5];
    const float* gate_lin2_w = (const float*)d_in[6];
    const float* gate_att_l = (const float*)d_in[7];
    const float* gate_att_r = (const float*)d_in[8];
    const float* gate_bias = (const float*)d_in[9];
    const float* grus_wi = (const float*)d_in[10];
    const float* grus_wh = (const float*)d_in[11];
    const float* grus_bi = (const float*)d_in[12];
    const float* grus_bh = (const float*)d_in[13];
    const float* atom_w = (const float*)d_in[14];
    const float* atom_att_src = (const float*)d_in[15];
    const float* atom_att_dst = (const float*)d_in[16];
    const float* atom_bias = (const float*)d_in[17];
    const float* mol_w = (const float*)d_in[18];
    const float* mol_att_src = (const float*)d_in[19];
    const float* mol_att_dst = (const float*)d_in[20];
    const float* mol_bias = (const float*)d_in[21];
    const float* lin2_w = (const float*)d_in[22];
    const float* lin2_b = (const float*)d_in[23];
    const float* fcm0_w = (const float*)d_in[24];
    const float* fcm0_b = (const float*)d_in[25];
    const float* fcm1_w = (const float*)d_in[26];
    const float* fcm1_b = (const float*)d_in[27];
    const float* fcm2_w = (const float*)d_in[28];
    const float* fcm2_b = (const float*)d_in[29];
    const float* fc0_w = (const float*)d_in[30];
    const float* fc0_b = (const float*)d_in[31];
    const float* fc1_w = (const float*)d_in[32];
    const float* fc1_b = (const float*)d_in[33];
    const float* fc2_w = (const float*)d_in[34];
    const float* fc2_b = (const float*)d_in[35];
    const float* fc3_w = (const float*)d_in[36];
    const float* fc3_b = (const float*)d_in[37];
    const float* fc4_w = (const float*)d_in[38];
    const float* fc4_b = (const float*)d_in[39];
    const int* edge_index = (const int*)d_in[40];
    const int* batch = (const int*)d_in[41];
    float* out_final = (float*)d_out;

    const int N = in_sizes[0] / 64;
    const int E = in_sizes[1] / 16;
    const int G = in_sizes[2] / 200;
    const int* srcE = edge_index;
    const int* dstE = edge_index + E;

    // ---- adaptive workspace layout (bytes) ----
    char* base = (char*)d_ws;
    size_t off = 0;
    auto alloc = [&](size_t bytes) -> char* {
        char* p = base + off;
        off += (bytes + 255) & ~(size_t)255;
        return p;
    };
    bf16* xh = (bf16*)alloc((size_t)N * 256 * 2);      // hidden state (bf16)
    float* hagg = (float*)alloc((size_t)N * 256 * 4);  // agg target / GAT t / heads alias
    float* outg = (float*)alloc((size_t)G * 256 * 4);  // graph state
    float* hgr = (float*)alloc((size_t)G * 256 * 4);   // graph agg target
    float* elog = (float*)alloc((size_t)E * 4);
    float* eexp = (float*)alloc((size_t)E * 4);
    float* aedge = (float*)alloc((size_t)E * 4);
    unsigned* nkey = (unsigned*)alloc((size_t)N * 4);
    float* nsum = (float*)alloc((size_t)N * 4);
    float* ns1 = (float*)alloc((size_t)N * 4);
    float* ns2 = (float*)alloc((size_t)N * 4);
    unsigned* gkey = (unsigned*)alloc((size_t)G * 4);
    float* gsum = (float*)alloc((size_t)G * 4);
    float* wgb = (float*)alloc((size_t)G * 4);
    float* vbuf = (float*)alloc(1024 * 4);
    size_t fixed_bytes = off;
    if (fixed_bytes + (size_t)1280 * 4 * 1024 > ws_size) {
        // doesn't fit: encode ws_size into the output so we learn the budget
        fill_f32<<<cdiv(out_size, 256), 256, 0, stream>>>(out_final, (float)ws_size,
                                                          (size_t)out_size);
        return;
    }
    size_t work_bytes = ws_size - fixed_bytes;
    float* workf = (float*)(base + fixed_bytes);
    bf16* workb = (bf16*)(base + fixed_bytes);
    size_t work_floats = work_bytes / 4;
    int Nc1 = (int)(work_floats / 1280); if (Nc1 > N) Nc1 = N;   // pre-GEMM + S + hn
    int Nc2 = (int)(work_floats / 1024); if (Nc2 > N) Nc2 = N;   // S + hn only
    int Ec = (int)(work_bytes / 512);    if (Ec > E) Ec = E;     // bf16 [Ec,256]
    // heads alias into hagg (free by then): G*(512*3+128+256*2)*4 = 71MB < 134MB
    float* fbufA = hagg;
    float* fbufB = fbufA + (size_t)G * 512;
    float* fbufC = fbufB + (size_t)G * 512;
    float* f128 = fbufC + (size_t)G * 512;
    float* hm1 = f128 + (size_t)G * 128;
    float* hm2 = hm1 + (size_t)G * 256;

    // node GRU over chunk rows, xin fp32 (elu in loader), state xh bf16
    auto gru_node = [&](int l, const float* xin_base, int c0, int Mc, float* Sb, float* hnb) {
        const float* wi = grus_wi + (size_t)l * 768 * 256;
        const float* wh = grus_wh + (size_t)l * 768 * 256;
        const float* bi = grus_bi + (size_t)l * 768;
        const float* bh = grus_bh + (size_t)l * 768;
        launch_gemm<2, 1, 0, false, false, false>(stream, Mc, 512, 768,
            xin_base, xh + (size_t)c0 * 256, 0, nullptr, nullptr,
            wi, wh, bi, bh, Sb, nullptr, 768, nullptr, nullptr, nullptr, nullptr, nullptr);
        launch_gemm<4, 0, 0, false, false, false>(stream, Mc, 256, 256,
            nullptr, xh + (size_t)c0 * 256, 256, nullptr, nullptr,
            wh + (size_t)512 * 256, nullptr, bh + 512, nullptr, hnb, nullptr, 256,
            nullptr, nullptr, nullptr, nullptr, nullptr);
        gru_combine_k<true><<<Mc, 256, 0, stream>>>(Sb, hnb, nullptr, xh + (size_t)c0 * 256, Mc);
    };

    // ---- xh = lrelu(x @ lin1_w^T + lin1_b), stored bf16 ----
    launch_gemm<0, 0, 1, false, false, true>(stream, N, 64, 256, x, nullptr, 64,
        nullptr, nullptr, lin1_w, nullptr, lin1_b, nullptr, nullptr, xh, 256,
        nullptr, nullptr, nullptr, nullptr, nullptr);

    // ---- GATEConv ----
    fill_f32<<<cdiv(E, 256), 256, 0, stream>>>(elog, 0.f, (size_t)E);
    launch_gemm<1, 0, 1, true, false, false>(stream, E, 272, 256, nullptr, xh, 0,
        srcE, edge_attr, gate_lin1_w, nullptr, nullptr, nullptr, nullptr, nullptr, 0,
        gate_att_l, elog, nullptr, nullptr, nullptr);
    rowdot2_b<<<cdiv(N, 4), 256, 0, stream>>>(xh, gate_att_r, nullptr, ns1, nullptr, N);
    edge_add_lrelu<<<cdiv(E, 256), 256, 0, stream>>>(elog, ns1, dstE, E);
    fill_u32<<<cdiv(N, 256), 256, 0, stream>>>(nkey, KEY_NEG_INF, N);
    fill_f32<<<cdiv(N, 256), 256, 0, stream>>>(nsum, 0.f, (size_t)N);
    seg_max_k<<<cdiv(E, 256), 256, 0, stream>>>(elog, dstE, nkey, E);
    seg_exp_k<<<cdiv(E, 256), 256, 0, stream>>>(elog, dstE, nkey, eexp, nsum, E);
    seg_div_k<<<cdiv(E, 256), 256, 0, stream>>>(eexp, dstE, nsum, aedge, E);
    setbias_k<<<N, 256, 0, stream>>>(hagg, gate_bias, N);
    for (int e0 = 0; e0 < E; e0 += Ec) {
        int Mc = E - e0 < Ec ? E - e0 : Ec;
        launch_gemm<1, 0, 1, false, false, true>(stream, Mc, 272, 256, nullptr, xh, 0,
            srcE + e0, edge_attr + (size_t)e0 * 16, gate_lin1_w, nullptr, nullptr,
            nullptr, nullptr, workb, 256, nullptr, nullptr, nullptr, nullptr, nullptr);
        launch_gemm<4, 0, 0, false, true, false>(stream, Mc, 256, 256, nullptr, workb,
            256, nullptr, nullptr, gate_lin2_w, nullptr, nullptr, nullptr, nullptr,
            nullptr, 0, nullptr, nullptr, dstE + e0, aedge + e0, hagg);
    }
    for (int c0 = 0; c0 < N; c0 += Nc2) {
        int Mc = N - c0 < Nc2 ? N - c0 : Nc2;
        gru_node(0, hagg + (size_t)c0 * 256, c0, Mc, workf, workf + (size_t)Nc2 * 768);
    }

    // ---- GATConv l=0,1 ----
    for (int l = 0; l < 2; l++) {
        const float* aw = atom_w + (size_t)l * 256 * 256;
        matvecT_k<<<1, 256, 0, stream>>>(aw, atom_att_src + (size_t)l * 256, vbuf, 256, 256);
        matvecT_k<<<1, 256, 0, stream>>>(aw, atom_att_dst + (size_t)l * 256, vbuf + 256, 256, 256);
        rowdot2_b<<<cdiv(N, 4), 256, 0, stream>>>(xh, vbuf, vbuf + 256, ns1, ns2, N);
        pair_logit<<<cdiv(E, 256), 256, 0, stream>>>(elog, ns1, ns2, srcE, dstE, E);
        fill_u32<<<cdiv(N, 256), 256, 0, stream>>>(nkey, KEY_NEG_INF, N);
        fill_f32<<<cdiv(N, 256), 256, 0, stream>>>(nsum, 0.f, (size_t)N);
        seg_max_k<<<cdiv(E, 256), 256, 0, stream>>>(elog, dstE, nkey, E);
        seg_exp_k<<<cdiv(E, 256), 256, 0, stream>>>(elog, dstE, nkey, eexp, nsum, E);
        seg_div_k<<<cdiv(E, 256), 256, 0, stream>>>(eexp, dstE, nsum, aedge, E);
        // t = sum_e a_e * xh[src] -> hagg (linearity: h = t @ aw^T + bias)
        setbias_k<<<N, 256, 0, stream>>>(hagg, nullptr, N);
        scatter_rows_b<<<E, 256, 0, stream>>>(xh, srcE, aedge, dstE, hagg, E);
        for (int c0 = 0; c0 < N; c0 += Nc1) {
            int Mc = N - c0 < Nc1 ? N - c0 : Nc1;
            float* cbuf = workf;
            float* Sb = workf + (size_t)Nc1 * 256;
            float* hnb = Sb + (size_t)Nc1 * 768;
            launch_gemm<0, 0, 0, false, false, false>(stream, Mc, 256, 256,
                hagg + (size_t)c0 * 256, nullptr, 256, nullptr, nullptr, aw, nullptr,
                atom_bias + (size_t)l * 256, nullptr, cbuf, nullptr, 256,
                nullptr, nullptr, nullptr, nullptr, nullptr);
            gru_node(1 + l, cbuf, c0, Mc, Sb, hnb);
        }
    }

    // ---- attentive readout ----
    setbias_k<<<G, 256, 0, stream>>>(outg, nullptr, G);
    scatter_rows_b<<<N, 256, 0, stream>>>(xh, nullptr, nullptr, batch, outg, N);
    relu_inplace<<<cdiv(G, 1), 256, 0, stream>>>(outg, (size_t)G * 256);
    matvecT_k<<<1, 256, 0, stream>>>(mol_w, mol_att_dst, vbuf, 256, 256);       // v_dst
    matvecT_k<<<1, 256, 0, stream>>>(mol_w, mol_att_src, vbuf + 256, 256, 256); // v_src
    rowdot2_b<<<cdiv(N, 4), 256, 0, stream>>>(xh, vbuf + 256, nullptr, ns1, nullptr, N);
    int NcG = Nc1 < G ? Nc1 : G;
    for (int t = 0; t < 3; t++) {
        rowdot_f<<<cdiv(G, 4), 256, 0, stream>>>(outg, vbuf, wgb, G);
        node_logit<<<cdiv(N, 256), 256, 0, stream>>>(elog, ns1, wgb, batch, N);
        fill_u32<<<cdiv(G, 256), 256, 0, stream>>>(gkey, KEY_NEG_INF, G);
        fill_f32<<<cdiv(G, 256), 256, 0, stream>>>(gsum, 0.f, (size_t)G);
        seg_max_k<<<cdiv(N, 256), 256, 0, stream>>>(elog, batch, gkey, N);
        seg_exp_k<<<cdiv(N, 256), 256, 0, stream>>>(elog, batch, gkey, eexp, gsum, N);
        seg_div_k<<<cdiv(N, 256), 256, 0, stream>>>(eexp, batch, gsum, aedge, N);
        // t_g = sum_n a_n xh[n] -> hgr ; then per-chunk: (t_g@mol_w^T+bias) -> GRU
        setbias_k<<<G, 256, 0, stream>>>(hgr, nullptr, G);
        scatter_rows_b<<<N, 256, 0, stream>>>(xh, nullptr, aedge, batch, hgr, N);
        for (int c0 = 0; c0 < G; c0 += NcG) {
            int Mc = G - c0 < NcG ? G - c0 : NcG;
            float* cbuf = workf;
            float* Sb = workf + (size_t)NcG * 256;
            float* hnb = Sb + (size_t)NcG * 768;
            launch_gemm<0, 0, 0, false, false, false>(stream, Mc, 256, 256,
                hgr + (size_t)c0 * 256, nullptr, 256, nullptr, nullptr, mol_w, nullptr,
                mol_bias, nullptr, cbuf, nullptr, 256,
                nullptr, nullptr, nullptr, nullptr, nullptr);
            launch_gemm<3, 1, 0, false, false, false>(stream, Mc, 512, 768,
                cbuf, nullptr, 0, nullptr, outg + (size_t)c0 * 256,
                grus_wi + (size_t)3 * 768 * 256, grus_wh + (size_t)3 * 768 * 256,
                grus_bi + (size_t)3 * 768, grus_bh + (size_t)3 * 768, Sb, nullptr, 768,
                nullptr, nullptr, nullptr, nullptr, nullptr);
            launch_gemm<0, 0, 0, false, false, false>(stream, Mc, 256, 256,
                outg + (size_t)c0 * 256, nullptr, 256, nullptr, nullptr,
                grus_wh + (size_t)3 * 768 * 256 + (size_t)512 * 256, nullptr,
                grus_bh + (size_t)3 * 768 + 512, nullptr, hnb, nullptr, 256,
                nullptr, nullptr, nullptr, nullptr, nullptr);
            gru_combine_k<false><<<Mc, 256, 0, stream>>>(Sb, hnb, outg + (size_t)c0 * 256,
                                                         nullptr, Mc);
        }
    }

    // ---- heads (alias region in hagg) ----
    launch_gemm<0, 0, 0, false, false, false>(stream, G, 256, 256, outg, nullptr, 256,
        nullptr, nullptr, lin2_w, nullptr, lin2_b, nullptr, fbufA, nullptr, 512,
        nullptr, nullptr, nullptr, nullptr, nullptr);
    launch_gemm<0, 0, 3, false, false, false>(stream, G, 200, 256, mol_feats, nullptr,
        200, nullptr, nullptr, fcm0_w, nullptr, fcm0_b, nullptr, hm1, nullptr, 256,
        nullptr, nullptr, nullptr, nullptr, nullptr);
    launch_gemm<0, 0, 3, false, false, false>(stream, G, 256, 256, hm1, nullptr, 256,
        nullptr, nullptr, fcm1_w, nullptr, fcm1_b, nullptr, hm2, nullptr, 256,
        nullptr, nullptr, nullptr, nullptr, nullptr);
    launch_gemm<0, 0, 3, false, false, false>(stream, G, 256, 256, hm2, nullptr, 256,
        nullptr, nullptr, fcm2_w, nullptr, fcm2_b, nullptr, fbufA + 256, nullptr, 512,
        nullptr, nullptr, nullptr, nullptr, nullptr);
    launch_gemm<0, 0, 3, false, false, false>(stream, G, 512, 512, fbufA, nullptr, 512,
        nullptr, nullptr, fc0_w, nullptr, fc0_b, nullptr, fbufB, nullptr, 512,
        nullptr, nullptr, nullptr, nullptr, nullptr);
    launch_gemm<0, 0, 3, false, false, false>(stream, G, 512, 512, fbufB, nullptr, 512,
        nullptr, nullptr, fc1_w, nullptr, fc1_b, nullptr, fbufC, nullptr, 512,
        nullptr, nullptr, nullptr, nullptr, nullptr);
    launch_gemm<0, 0, 3, false, false, false>(stream, G, 512, 512, fbufC, nullptr, 512,
        nullptr, nullptr, fc2_w, nullptr, fc2_b, nullptr, fbufB, nullptr, 512,
        nullptr, nullptr, nullptr, nullptr, nullptr);
    launch_gemm<0, 0, 3, false, false, false>(stream, G, 512, 128, fbufB, nullptr, 512,
        nullptr, nullptr, fc3_w, nullptr, fc3_b, nullptr, f128, nullptr, 128,
        nullptr, nullptr, nullptr, nullptr, nullptr);
    fc4_k<<<cdiv(G, 4), 256, 0, stream>>>(f128, fc4_w, fc4_b, out_final, G);
}

// Round 5
// 9608.870 us; speedup vs baseline: 1.7154x; 1.7154x over previous
//
#include <hip/hip_runtime.h>
#include <hip/hip_bf16.h>
#include <math.h>

// ---------------------------------------------------------------------------
// AttentiveFP forward, MI355X. Round 5: split-bf16 (3-MFMA) GEMMs for ~fp32
// GEMM precision on the MFMA pipe. Weights packed hi||lo; A split in loader.
// ---------------------------------------------------------------------------

typedef unsigned short u16;
typedef u16 u16x8 __attribute__((ext_vector_type(8)));
typedef short s16x8 __attribute__((ext_vector_type(8)));
typedef float f32x4 __attribute__((ext_vector_type(4)));

__device__ __forceinline__ float u2f(u16 u) { return __uint_as_float(((unsigned)u) << 16); }
__device__ __forceinline__ u16 f2u(float f) {
    return __builtin_bit_cast(u16, __float2bfloat16(f));  // RTN
}

#define NEGS 0.01f

__device__ __forceinline__ unsigned fkey(float f) {
    unsigned u = __float_as_uint(f);
    return (u & 0x80000000u) ? ~u : (u | 0x80000000u);
}
__device__ __forceinline__ float funkey(unsigned k) {
    return (k & 0x80000000u) ? __uint_as_float(k ^ 0x80000000u) : __uint_as_float(~k);
}
#define KEY_NEG_INF 0x007FFFFFu

static inline int cdiv(int a, int b) { return (a + b - 1) / b; }

// ---------------- utility kernels ----------------
__global__ void fill_f32(float* p, float v, size_t n) {
    size_t i = (size_t)blockIdx.x * 256 + threadIdx.x;
    if (i < n) p[i] = v;
}
__global__ void fill_u32(unsigned* p, unsigned v, int n) {
    int i = blockIdx.x * 256 + threadIdx.x;
    if (i < n) p[i] = v;
}
__global__ void relu_inplace(float* p, size_t n) {
    size_t i = (size_t)blockIdx.x * 256 + threadIdx.x;
    if (i < n) p[i] = fmaxf(p[i], 0.f);
}
__global__ void matvecT_k(const float* W, const float* a, float* v, int K, int Jout) {
    int j = blockIdx.x * 256 + threadIdx.x;
    if (j >= Jout) return;
    float s = 0.f;
    for (int k = 0; k < K; k++) s += W[(size_t)k * Jout + j] * a[k];
    v[j] = s;
}
__global__ void edge_add_lrelu(float* elog, const float* r, const int* dsti, int E) {
    int i = blockIdx.x * 256 + threadIdx.x;
    if (i < E) {
        float v = elog[i] + r[dsti[i]];
        elog[i] = v > 0.f ? v : NEGS * v;
    }
}
__global__ void pair_logit(float* elog, const float* s, const float* d,
                           const int* srci, const int* dsti, int E) {
    int i = blockIdx.x * 256 + threadIdx.x;
    if (i < E) {
        float v = s[srci[i]] + d[dsti[i]];
        elog[i] = v > 0.f ? v : NEGS * v;
    }
}
__global__ void node_logit(float* nlog, const float* asrc, const float* wg,
                           const int* batch, int N) {
    int i = blockIdx.x * 256 + threadIdx.x;
    if (i < N) {
        float v = asrc[i] + wg[batch[i]];
        nlog[i] = v > 0.f ? v : NEGS * v;
    }
}
__global__ void seg_max_k(const float* logit, const int* idx, unsigned* key, int n) {
    int i = blockIdx.x * 256 + threadIdx.x;
    if (i < n) atomicMax(&key[idx[i]], fkey(logit[i]));
}
__global__ void seg_exp_k(const float* logit, const int* idx, const unsigned* key,
                          float* ex, float* sum, int n) {
    int i = blockIdx.x * 256 + threadIdx.x;
    if (i < n) {
        float e = expf(logit[i] - funkey(key[idx[i]]));
        ex[i] = e;
        atomicAdd(&sum[idx[i]], e);
    }
}
__global__ void seg_div_k(const float* ex, const int* idx, const float* sum,
                          float* a, int n) {
    int i = blockIdx.x * 256 + threadIdx.x;
    if (i < n) a[i] = ex[i] / (sum[idx[i]] + 1e-16f);
}
__global__ void scatter_rows_b(const u16* V, const int* gsrc, const float* sc,
                               const int* gdst, float* dst, int M) {
    int r = blockIdx.x;
    if (r >= M) return;
    int c = threadIdx.x;
    int vr = gsrc ? gsrc[r] : r;
    float v = u2f(V[(size_t)vr * 256 + c]);
    if (sc) v *= sc[r];
    atomicAdd(&dst[(size_t)gdst[r] * 256 + c], v);
}
__global__ void rowdot2_b(const u16* X, const float* v1, const float* v2,
                          float* o1, float* o2, int M) {
    int r = blockIdx.x * 4 + (threadIdx.x >> 6);
    int lane = threadIdx.x & 63;
    if (r >= M) return;
    const u16* row = X + (size_t)r * 256 + lane * 4;
    float p1 = 0.f, p2 = 0.f;
#pragma unroll
    for (int q = 0; q < 4; q++) {
        float xv = u2f(row[q]);
        p1 += xv * v1[lane * 4 + q];
        if (v2) p2 += xv * v2[lane * 4 + q];
    }
    for (int off = 32; off; off >>= 1) {
        p1 += __shfl_down(p1, off);
        if (v2) p2 += __shfl_down(p2, off);
    }
    if (lane == 0) {
        o1[r] = p1;
        if (v2) o2[r] = p2;
    }
}
__global__ void rowdot_f(const float* X, const float* v1, float* o1, int M) {
    int r = blockIdx.x * 4 + (threadIdx.x >> 6);
    int lane = threadIdx.x & 63;
    if (r >= M) return;
    float4 a = ((const float4*)(X + (size_t)r * 256))[lane];
    float4 b = ((const float4*)v1)[lane];
    float p1 = a.x * b.x + a.y * b.y + a.z * b.z + a.w * b.w;
    for (int off = 32; off; off >>= 1) p1 += __shfl_down(p1, off);
    if (lane == 0) o1[r] = p1;
}
template <bool HB>
__global__ void gru_combine_k(const float* S, const float* hn, float* hf, u16* hb, int M) {
    int m = blockIdx.x;
    if (m >= M) return;
    int c = threadIdx.x;
    float sr = S[(size_t)m * 768 + c];
    float sz = S[(size_t)m * 768 + 256 + c];
    float sn = S[(size_t)m * 768 + 512 + c];
    float hnv = hn[(size_t)m * 256 + c];
    float r = 1.f / (1.f + expf(-sr));
    float z = 1.f / (1.f + expf(-sz));
    float nv = tanhf(sn - hnv + r * hnv);
    float hv = HB ? u2f(hb[(size_t)m * 256 + c]) : hf[(size_t)m * 256 + c];
    float o = fmaxf((1.f - z) * nv + z * hv, 0.f);
    if (HB) hb[(size_t)m * 256 + c] = f2u(o);
    else hf[(size_t)m * 256 + c] = o;
}
__global__ void fc4_k(const float* X, const float* w, const float* b, float* out, int G) {
    int g = blockIdx.x * 4 + (threadIdx.x >> 6);
    int lane = threadIdx.x & 63;
    if (g >= G) return;
    float2 xv = ((const float2*)(X + (size_t)g * 128))[lane];
    float2 wv = ((const float2*)w)[lane];
    float p = xv.x * wv.x + xv.y * wv.y;
    for (int off = 32; off; off >>= 1) p += __shfl_down(p, off);
    if (lane == 0) out[g] = p + b[0];
}

// ---------------- weight pre-pack (hi||lo) into MFMA operand order ----------
// chunk c: n = nblk*128+((c>>6)&7)*16+(c&15), k = kiter*32+((c>>4)&3)*8+j
__global__ void pack_w(const float* s1, const float* s2, int K1, int Ksrc,
                       int Nout, int Kp, u16* dst) {
    int idx = blockIdx.x * 256 + threadIdx.x;
    int kiters = Kp >> 5;
    int total = (Nout >> 7) * kiters * 512;
    if (idx >= total) return;
    int c = idx & 511;
    int rest = idx >> 9;
    int ki = rest % kiters, nb = rest / kiters;
    int n = (nb << 7) + (((c >> 6) & 7) << 4) + (c & 15);
    int k0 = (ki << 5) + (((c >> 4) & 3) << 3);
    u16x8 vh, vl;
#pragma unroll
    for (int j = 0; j < 8; j++) {
        int k = k0 + j;
        float f = 0.f;
        if (k < K1) f = s1[(size_t)n * K1 + k];
        else if (k < Ksrc) f = s2[(size_t)n * (Ksrc - K1) + (k - K1)];
        u16 h = f2u(f);
        vh[j] = h;
        vl[j] = f2u(f - u2f(h));
    }
    ((u16x8*)dst)[idx] = vh;
    ((u16x8*)dst)[idx + total] = vl;
}

// ---------------- split-bf16 MFMA GEMM ----------------
// C[m,n] = act(sum_k A[m,k]*W[n,k] + b1[n] + b2[n]); 3 MFMAs: hh + lh + hl
// ALD: 0 bf16 Ab(lda); 1 f32 Af(lda), zero-pad k>=Ksrc;
//      2 [xh[gidx[m]] bf16 (256) | edge_attr f32 (16) | 0];
//      3 [elu(f32 Af) (256) | bf16 Ab (256)]; 4 [elu(f32 Af) | f32 X2f]
// ACT: 0 none, 1 lrelu, 3 silu
// EPI: 0 f32 store; 1 bf16 store; 2 DOTV; 3 SCAT
struct p8 { u16x8 hi, lo; };
__device__ __forceinline__ u16x8 zero8() {
    u16x8 z;
#pragma unroll
    for (int j = 0; j < 8; j++) z[j] = 0;
    return z;
}
__device__ __forceinline__ p8 sp_zero() { p8 r; r.hi = zero8(); r.lo = zero8(); return r; }
__device__ __forceinline__ p8 sp_b(const u16* p) {
    p8 r;
    r.hi = *(const u16x8*)p;
    r.lo = zero8();
    return r;
}
__device__ __forceinline__ p8 sp_f(const float* p) {
    p8 r;
#pragma unroll
    for (int j = 0; j < 8; j++) {
        float x = p[j];
        u16 h = f2u(x);
        r.hi[j] = h;
        r.lo[j] = f2u(x - u2f(h));
    }
    return r;
}
__device__ __forceinline__ p8 sp_eluf(const float* p) {
    p8 r;
#pragma unroll
    for (int j = 0; j < 8; j++) {
        float x = p[j];
        float e = x > 0.f ? x : expm1f(x);
        u16 h = f2u(e);
        r.hi[j] = h;
        r.lo[j] = f2u(e - u2f(h));
    }
    return r;
}

template <int ALD>
__device__ __forceinline__ p8 ldA(bool valid, int k, int Ksrc, const u16* ab,
                                  const float* af, const float* x2) {
    if (!valid) return sp_zero();
    if (ALD == 0) return sp_b(ab + k);
    if (ALD == 1) {
        if (k >= Ksrc) return sp_zero();
        return sp_f(af + k);
    }
    if (ALD == 2) {
        if (k < 256) return sp_b(ab + k);
        if (k < 272) return sp_f(x2 + (k - 256));
        return sp_zero();
    }
    if (ALD == 3) {
        if (k < 256) return sp_eluf(af + k);
        return sp_b(ab + (k - 256));
    }
    if (k < 256) return sp_eluf(af + k);
    return sp_f(x2 + (k - 256));
}

template <int ACT>
__device__ __forceinline__ float actf(float v) {
    if (ACT == 1) return v > 0.f ? v : NEGS * v;
    if (ACT == 3) return v / (1.f + expf(-v));
    return v;
}

template <int ALD, int ACT, int EPI>
__global__ __launch_bounds__(256, 2) void mgemm(
    int M, int Kp, int Ksrc,
    const float* Af, int lda, const u16* Ab,
    const int* gidx, const float* X2f, const u16* Wp,
    const float* b1, const float* b2,
    float* Cf, u16* Cb, int ldc,
    const float* attv, float* dotout,
    const int* didx, const float* escale, float* scat) {
    __shared__ u16x8 lsAh[512];
    __shared__ u16x8 lsAl[512];
    __shared__ u16x8 lsWh[512];
    __shared__ u16x8 lsWl[512];
    const int t = threadIdx.x;
    const int m0 = blockIdx.x * 128;
    const int nb = blockIdx.y;
    const int kiters = Kp >> 5;
    const int r0 = ((t >> 6) << 4) | (t & 15);
    const int kq = ((t >> 4) & 3) << 3;
    const int mA[2] = {m0 + r0, m0 + r0 + 64};
    const u16* abr[2];
    const float* afr[2];
    const float* x2r[2];
    bool val[2];
#pragma unroll
    for (int h = 0; h < 2; h++) {
        int m = mA[h];
        val[h] = (m < M);
        int ms = val[h] ? m : 0;
        abr[h] = nullptr; afr[h] = nullptr; x2r[h] = nullptr;
        if (ALD == 0) {
            abr[h] = Ab + (size_t)ms * lda;
        } else if (ALD == 1) {
            afr[h] = Af + (size_t)ms * lda;
        } else if (ALD == 2) {
            abr[h] = Ab + (size_t)gidx[ms] * 256;
            x2r[h] = X2f + (size_t)ms * 16;
        } else if (ALD == 3) {
            afr[h] = Af + (size_t)ms * 256;
            abr[h] = Ab + (size_t)ms * 256;
        } else {
            afr[h] = Af + (size_t)ms * 256;
            x2r[h] = X2f + (size_t)ms * 256;
        }
    }
    const int wave = t >> 6, lane = t & 63;
    const int wm = (wave >> 1) << 6, wn = (wave & 1) << 6;
    f32x4 acc[4][4];
#pragma unroll
    for (int i = 0; i < 4; i++)
#pragma unroll
        for (int j = 0; j < 4; j++) {
            acc[i][j][0] = 0.f; acc[i][j][1] = 0.f; acc[i][j][2] = 0.f; acc[i][j][3] = 0.f;
        }
    const u16x8* wh0 = (const u16x8*)Wp + ((size_t)nb * kiters << 9);
    const u16x8* wl0 = wh0 + ((size_t)gridDim.y * kiters << 9);
    for (int ki = 0; ki < kiters; ki++) {
        int kb = (ki << 5) + kq;
        p8 a0 = ldA<ALD>(val[0], kb, Ksrc, abr[0], afr[0], x2r[0]);
        p8 a1 = ldA<ALD>(val[1], kb, Ksrc, abr[1], afr[1], x2r[1]);
        lsAh[t] = a0.hi; lsAl[t] = a0.lo;
        lsAh[t + 256] = a1.hi; lsAl[t + 256] = a1.lo;
        const u16x8* wsh = wh0 + ((size_t)ki << 9);
        const u16x8* wsl = wl0 + ((size_t)ki << 9);
        lsWh[t] = wsh[t]; lsWh[t + 256] = wsh[t + 256];
        lsWl[t] = wsl[t]; lsWl[t + 256] = wsl[t + 256];
        __syncthreads();
        s16x8 ah[4], al[4], wh[4], wl[4];
#pragma unroll
        for (int f = 0; f < 4; f++) {
            int ai = ((wm >> 4) + f) * 64 + lane;
            int wi = ((wn >> 4) + f) * 64 + lane;
            ah[f] = __builtin_bit_cast(s16x8, lsAh[ai]);
            al[f] = __builtin_bit_cast(s16x8, lsAl[ai]);
            wh[f] = __builtin_bit_cast(s16x8, lsWh[wi]);
            wl[f] = __builtin_bit_cast(s16x8, lsWl[wi]);
        }
#pragma unroll
        for (int fi = 0; fi < 4; fi++)
#pragma unroll
            for (int fj = 0; fj < 4; fj++) {
                acc[fi][fj] = __builtin_amdgcn_mfma_f32_16x16x32_bf16(
                    ah[fi], wh[fj], acc[fi][fj], 0, 0, 0);
                acc[fi][fj] = __builtin_amdgcn_mfma_f32_16x16x32_bf16(
                    al[fi], wh[fj], acc[fi][fj], 0, 0, 0);
                acc[fi][fj] = __builtin_amdgcn_mfma_f32_16x16x32_bf16(
                    ah[fi], wl[fj], acc[fi][fj], 0, 0, 0);
            }
        __syncthreads();
    }
    const int col = lane & 15, quad = lane >> 4;
    const int n_base = nb * 128 + wn;
    if (EPI == 2) {
        float dp[4][4] = {};
#pragma unroll
        for (int fi = 0; fi < 4; fi++)
#pragma unroll
            for (int fj = 0; fj < 4; fj++) {
                int nn = n_base + fj * 16 + col;
                float av = attv[nn];
#pragma unroll
                for (int r = 0; r < 4; r++) dp[fi][r] += actf<ACT>(acc[fi][fj][r]) * av;
            }
#pragma unroll
        for (int fi = 0; fi < 4; fi++)
#pragma unroll
            for (int r = 0; r < 4; r++) {
                float p = dp[fi][r];
                p += __shfl_down(p, 8);
                p += __shfl_down(p, 4);
                p += __shfl_down(p, 2);
                p += __shfl_down(p, 1);
                int mm = m0 + wm + fi * 16 + quad * 4 + r;
                if (col == 0 && mm < M) atomicAdd(dotout + mm, p);
            }
    } else if (EPI == 3) {
#pragma unroll
        for (int fi = 0; fi < 4; fi++)
#pragma unroll
            for (int r = 0; r < 4; r++) {
                int mm = m0 + wm + fi * 16 + quad * 4 + r;
                if (mm >= M) continue;
                int d = didx[mm];
                float s = escale[mm];
                float* rowp = scat + (size_t)d * 256;
#pragma unroll
                for (int fj = 0; fj < 4; fj++) {
                    int nn = n_base + fj * 16 + col;
                    atomicAdd(rowp + nn, actf<ACT>(acc[fi][fj][r]) * s);
                }
            }
    } else {
#pragma unroll
        for (int fj = 0; fj < 4; fj++) {
            int nn = n_base + fj * 16 + col;
            float bb = (b1 ? b1[nn] : 0.f) + (b2 ? b2[nn] : 0.f);
#pragma unroll
            for (int fi = 0; fi < 4; fi++)
#pragma unroll
                for (int r = 0; r < 4; r++) {
                    int mm = m0 + wm + fi * 16 + quad * 4 + r;
                    if (mm >= M) continue;
                    float v = actf<ACT>(acc[fi][fj][r] + bb);
                    if (EPI == 1) Cb[(size_t)mm * ldc + nn] = f2u(v);
                    else Cf[(size_t)mm * ldc + nn] = v;
                }
        }
    }
}

extern "C" void kernel_launch(void* const* d_in, const int* in_sizes, int n_in,
                              void* d_out, int out_size, void* d_ws, size_t ws_size,
                              hipStream_t stream) {
    const float* x = (const float*)d_in[0];
    const float* edge_attr = (const float*)d_in[1];
    const float* mol_feats = (const float*)d_in[2];
    const float* lin1_w = (const float*)d_in[3];
    const float* lin1_b = (const float*)d_in[4];
    const float* gate_lin1_w = (const float*)d_in[5];
    const float* gate_lin2_w = (const float*)d_in[6];
    const float* gate_att_l = (const float*)d_in[7];
    const float* gate_att_r = (const float*)d_in[8];
    const float* gate_bias = (const float*)d_in[9];
    const float* grus_wi = (const float*)d_in[10];
    const float* grus_wh = (const float*)d_in[11];
    const float* grus_bi = (const float*)d_in[12];
    const float* grus_bh = (const float*)d_in[13];
    const float* atom_w = (const float*)d_in[14];
    const float* atom_att_src = (const float*)d_in[15];
    const float* atom_att_dst = (const float*)d_in[16];
    const float* atom_bias = (const float*)d_in[17];
    const float* mol_w = (const float*)d_in[18];
    const float* mol_att_src = (const float*)d_in[19];
    const float* mol_att_dst = (const float*)d_in[20];
    const float* mol_bias = (const float*)d_in[21];
    const float* lin2_w = (const float*)d_in[22];
    const float* lin2_b = (const float*)d_in[23];
    const float* fcm0_w = (const float*)d_in[24];
    const float* fcm0_b = (const float*)d_in[25];
    const float* fcm1_w = (const float*)d_in[26];
    const float* fcm1_b = (const float*)d_in[27];
    const float* fcm2_w = (const float*)d_in[28];
    const float* fcm2_b = (const float*)d_in[29];
    const float* fc0_w = (const float*)d_in[30];
    const float* fc0_b = (const float*)d_in[31];
    const float* fc1_w = (const float*)d_in[32];
    const float* fc1_b = (const float*)d_in[33];
    const float* fc2_w = (const float*)d_in[34];
    const float* fc2_b = (const float*)d_in[35];
    const float* fc3_w = (const float*)d_in[36];
    const float* fc3_b = (const float*)d_in[37];
    const float* fc4_w = (const float*)d_in[38];
    const float* fc4_b = (const float*)d_in[39];
    const int* edge_index = (const int*)d_in[40];
    const int* batch = (const int*)d_in[41];
    float* out_final = (float*)d_out;

    const int N = in_sizes[0] / 64;
    const int E = in_sizes[1] / 16;
    const int G = in_sizes[2] / 200;
    const int* srcE = edge_index;
    const int* dstE = edge_index + E;

    // ---- workspace layout ----
    char* base = (char*)d_ws;
    size_t off = 0;
    auto alloc = [&](size_t bytes) -> char* {
        char* p = base + off;
        off += (bytes + 255) & ~(size_t)255;
        return p;
    };
    u16* xh = (u16*)alloc((size_t)N * 256 * 2);
    float* hagg = (float*)alloc((size_t)N * 256 * 4);
    float* outg = (float*)alloc((size_t)G * 256 * 4);
    float* hgr = (float*)alloc((size_t)G * 256 * 4);
    float* elog = (float*)alloc((size_t)E * 4);
    float* eexp = (float*)alloc((size_t)E * 4);
    float* aedge = (float*)alloc((size_t)E * 4);
    unsigned* nkey = (unsigned*)alloc((size_t)N * 4);
    float* nsum = (float*)alloc((size_t)N * 4);
    float* ns1 = (float*)alloc((size_t)N * 4);
    float* ns2 = (float*)alloc((size_t)N * 4);
    unsigned* gkey = (unsigned*)alloc((size_t)G * 4);
    float* gsum = (float*)alloc((size_t)G * 4);
    float* wgb = (float*)alloc((size_t)G * 4);
    float* vbuf = (float*)alloc(1024 * 4);
    // packed weights: hi||lo, so 2x elements
    u16* pk_lin1 = (u16*)alloc(256 * 64 * 2 * 2);
    u16* pk_g1 = (u16*)alloc(256 * 288 * 2 * 2);
    u16* pk_g2 = (u16*)alloc(256 * 256 * 2 * 2);
    u16* pk_gru_s[4];
    u16* pk_gru_hn[4];
    for (int l = 0; l < 4; l++) {
        pk_gru_s[l] = (u16*)alloc(768 * 512 * 2 * 2);
        pk_gru_hn[l] = (u16*)alloc(256 * 256 * 2 * 2);
    }
    u16* pk_atom[2];
    for (int l = 0; l < 2; l++) pk_atom[l] = (u16*)alloc(256 * 256 * 2 * 2);
    u16* pk_mol = (u16*)alloc(256 * 256 * 2 * 2);
    u16* pk_lin2 = (u16*)alloc(256 * 256 * 2 * 2);
    u16* pk_fcm0 = (u16*)alloc(256 * 224 * 2 * 2);
    u16* pk_fcm1 = (u16*)alloc(256 * 256 * 2 * 2);
    u16* pk_fcm2 = (u16*)alloc(256 * 256 * 2 * 2);
    u16* pk_fc0 = (u16*)alloc(512 * 512 * 2 * 2);
    u16* pk_fc1 = (u16*)alloc(512 * 512 * 2 * 2);
    u16* pk_fc2 = (u16*)alloc(512 * 512 * 2 * 2);
    u16* pk_fc3 = (u16*)alloc(128 * 512 * 2 * 2);
    size_t fixed_bytes = off;
    if (fixed_bytes + (size_t)2 * 1024 * 1024 > ws_size) {
        fill_f32<<<cdiv(out_size, 256), 256, 0, stream>>>(out_final, (float)ws_size,
                                                          (size_t)out_size);
        return;
    }
    char* workp = base + fixed_bytes;
    size_t avail = ws_size - fixed_bytes;
    // per-row: cbuf f32 (1024) + S f32 (3072) + hn f32 (1024) = 5120 B
    size_t McS = (avail - 4096) / 5120;
    int Mc = (int)(McS < (size_t)N ? McS : (size_t)N);
    float* cbuf = (float*)workp;
    float* Sbuf = (float*)(workp + (((size_t)Mc * 1024 + 255) & ~(size_t)255));
    float* hnbuf = (float*)((char*)Sbuf + (size_t)Mc * 3072);
    // heads alias into hagg
    float* fbufA = hagg;
    float* fbufB = fbufA + (size_t)G * 512;
    float* fbufC = fbufB + (size_t)G * 512;
    float* f128 = fbufC + (size_t)G * 512;
    float* hm1 = f128 + (size_t)G * 128;
    float* hm2 = hm1 + (size_t)G * 256;

    // ---- pack all weights ----
    auto pack = [&](const float* s1, const float* s2, int K1, int Ksrc, int Nout,
                    int Kp, u16* dst) {
        int total = (Nout >> 7) * (Kp >> 5) * 512;
        pack_w<<<cdiv(total, 256), 256, 0, stream>>>(s1, s2, K1, Ksrc, Nout, Kp, dst);
    };
    pack(lin1_w, nullptr, 64, 64, 256, 64, pk_lin1);
    pack(gate_lin1_w, nullptr, 272, 272, 256, 288, pk_g1);
    pack(gate_lin2_w, nullptr, 256, 256, 256, 256, pk_g2);
    for (int l = 0; l < 4; l++) {
        pack(grus_wi + (size_t)l * 768 * 256, grus_wh + (size_t)l * 768 * 256,
             256, 512, 768, 512, pk_gru_s[l]);
        pack(grus_wh + (size_t)l * 768 * 256 + (size_t)512 * 256, nullptr,
             256, 256, 256, 256, pk_gru_hn[l]);
    }
    for (int l = 0; l < 2; l++)
        pack(atom_w + (size_t)l * 256 * 256, nullptr, 256, 256, 256, 256, pk_atom[l]);
    pack(mol_w, nullptr, 256, 256, 256, 256, pk_mol);
    pack(lin2_w, nullptr, 256, 256, 256, 256, pk_lin2);
    pack(fcm0_w, nullptr, 200, 200, 256, 224, pk_fcm0);
    pack(fcm1_w, nullptr, 256, 256, 256, 256, pk_fcm1);
    pack(fcm2_w, nullptr, 256, 256, 256, 256, pk_fcm2);
    pack(fc0_w, nullptr, 512, 512, 512, 512, pk_fc0);
    pack(fc1_w, nullptr, 512, 512, 512, 512, pk_fc1);
    pack(fc2_w, nullptr, 512, 512, 512, 512, pk_fc2);
    pack(fc3_w, nullptr, 512, 512, 128, 512, pk_fc3);

#define NIL nullptr, nullptr, nullptr, nullptr, nullptr

    // node GRU layer: hagg(f32) --W,b--> cbuf(f32) --GRU l--> xh(bf16)
    auto node_gru = [&](int l, const u16* WpT, const float* bT) {
        const float* bi = grus_bi + (size_t)l * 768;
        const float* bh = grus_bh + (size_t)l * 768;
        for (int c0 = 0; c0 < N; c0 += Mc) {
            int Ms = N - c0 < Mc ? N - c0 : Mc;
            int gx = cdiv(Ms, 128);
            mgemm<1, 0, 0><<<dim3(gx, 2), 256, 0, stream>>>(Ms, 256, 256,
                hagg + (size_t)c0 * 256, 256, nullptr, nullptr, nullptr,
                WpT, bT, nullptr, cbuf, nullptr, 256, NIL);
            mgemm<3, 0, 0><<<dim3(gx, 6), 256, 0, stream>>>(Ms, 512, 512,
                cbuf, 256, xh + (size_t)c0 * 256, nullptr, nullptr,
                pk_gru_s[l], bi, bh, Sbuf, nullptr, 768, NIL);
            mgemm<0, 0, 0><<<dim3(gx, 2), 256, 0, stream>>>(Ms, 256, 256,
                nullptr, 256, xh + (size_t)c0 * 256, nullptr, nullptr,
                pk_gru_hn[l], bh + 512, nullptr, hnbuf, nullptr, 256, NIL);
            gru_combine_k<true><<<Ms, 256, 0, stream>>>(Sbuf, hnbuf, nullptr,
                                                        xh + (size_t)c0 * 256, Ms);
        }
    };

    // ---- xh = lrelu(x @ lin1_w^T + lin1_b) ----
    mgemm<1, 1, 1><<<dim3(cdiv(N, 128), 2), 256, 0, stream>>>(N, 64, 64,
        x, 64, nullptr, nullptr, nullptr, pk_lin1, lin1_b, nullptr,
        nullptr, xh, 256, NIL);

    // ---- GATEConv ----
    fill_f32<<<cdiv(E, 256), 256, 0, stream>>>(elog, 0.f, (size_t)E);
    mgemm<2, 1, 2><<<dim3(cdiv(E, 128), 2), 256, 0, stream>>>(E, 288, 272,
        nullptr, 0, xh, srcE, edge_attr, pk_g1, nullptr, nullptr,
        nullptr, nullptr, 0, gate_att_l, elog, nullptr, nullptr, nullptr);
    rowdot2_b<<<cdiv(N, 4), 256, 0, stream>>>(xh, gate_att_r, nullptr, ns1, nullptr, N);
    edge_add_lrelu<<<cdiv(E, 256), 256, 0, stream>>>(elog, ns1, dstE, E);
    fill_u32<<<cdiv(N, 256), 256, 0, stream>>>(nkey, KEY_NEG_INF, N);
    fill_f32<<<cdiv(N, 256), 256, 0, stream>>>(nsum, 0.f, (size_t)N);
    seg_max_k<<<cdiv(E, 256), 256, 0, stream>>>(elog, dstE, nkey, E);
    seg_exp_k<<<cdiv(E, 256), 256, 0, stream>>>(elog, dstE, nkey, eexp, nsum, E);
    seg_div_k<<<cdiv(E, 256), 256, 0, stream>>>(eexp, dstE, nsum, aedge, E);
    fill_f32<<<(int)(((size_t)N * 256 + 255) / 256), 256, 0, stream>>>(
        hagg, 0.f, (size_t)N * 256);
    mgemm<2, 1, 3><<<dim3(cdiv(E, 128), 2), 256, 0, stream>>>(E, 288, 272,
        nullptr, 0, xh, srcE, edge_attr, pk_g1, nullptr, nullptr,
        nullptr, nullptr, 0, nullptr, nullptr, dstE, aedge, hagg);
    node_gru(0, pk_g2, gate_bias);

    // ---- GATConv l=0,1 ----
    for (int l = 0; l < 2; l++) {
        const float* aw = atom_w + (size_t)l * 256 * 256;
        matvecT_k<<<1, 256, 0, stream>>>(aw, atom_att_src + (size_t)l * 256, vbuf, 256, 256);
        matvecT_k<<<1, 256, 0, stream>>>(aw, atom_att_dst + (size_t)l * 256, vbuf + 256, 256, 256);
        rowdot2_b<<<cdiv(N, 4), 256, 0, stream>>>(xh, vbuf, vbuf + 256, ns1, ns2, N);
        pair_logit<<<cdiv(E, 256), 256, 0, stream>>>(elog, ns1, ns2, srcE, dstE, E);
        fill_u32<<<cdiv(N, 256), 256, 0, stream>>>(nkey, KEY_NEG_INF, N);
        fill_f32<<<cdiv(N, 256), 256, 0, stream>>>(nsum, 0.f, (size_t)N);
        seg_max_k<<<cdiv(E, 256), 256, 0, stream>>>(elog, dstE, nkey, E);
        seg_exp_k<<<cdiv(E, 256), 256, 0, stream>>>(elog, dstE, nkey, eexp, nsum, E);
        seg_div_k<<<cdiv(E, 256), 256, 0, stream>>>(eexp, dstE, nsum, aedge, E);
        fill_f32<<<(int)(((size_t)N * 256 + 255) / 256), 256, 0, stream>>>(
            hagg, 0.f, (size_t)N * 256);
        scatter_rows_b<<<E, 256, 0, stream>>>(xh, srcE, aedge, dstE, hagg, E);
        node_gru(1 + l, pk_atom[l], atom_bias + (size_t)l * 256);
    }

    // ---- attentive readout ----
    fill_f32<<<(int)(((size_t)G * 256 + 255) / 256), 256, 0, stream>>>(
        outg, 0.f, (size_t)G * 256);
    scatter_rows_b<<<N, 256, 0, stream>>>(xh, nullptr, nullptr, batch, outg, N);
    relu_inplace<<<(int)(((size_t)G * 256 + 255) / 256), 256, 0, stream>>>(
        outg, (size_t)G * 256);
    matvecT_k<<<1, 256, 0, stream>>>(mol_w, mol_att_dst, vbuf, 256, 256);
    matvecT_k<<<1, 256, 0, stream>>>(mol_w, mol_att_src, vbuf + 256, 256, 256);
    rowdot2_b<<<cdiv(N, 4), 256, 0, stream>>>(xh, vbuf + 256, nullptr, ns1, nullptr, N);
    const float* bi3 = grus_bi + (size_t)3 * 768;
    const float* bh3 = grus_bh + (size_t)3 * 768;
    int McG = Mc < G ? Mc : G;
    for (int t = 0; t < 3; t++) {
        rowdot_f<<<cdiv(G, 4), 256, 0, stream>>>(outg, vbuf, wgb, G);
        node_logit<<<cdiv(N, 256), 256, 0, stream>>>(elog, ns1, wgb, batch, N);
        fill_u32<<<cdiv(G, 256), 256, 0, stream>>>(gkey, KEY_NEG_INF, G);
        fill_f32<<<cdiv(G, 256), 256, 0, stream>>>(gsum, 0.f, (size_t)G);
        seg_max_k<<<cdiv(N, 256), 256, 0, stream>>>(elog, batch, gkey, N);
        seg_exp_k<<<cdiv(N, 256), 256, 0, stream>>>(elog, batch, gkey, eexp, gsum, N);
        seg_div_k<<<cdiv(N, 256), 256, 0, stream>>>(eexp, batch, gsum, aedge, N);
        fill_f32<<<(int)(((size_t)G * 256 + 255) / 256), 256, 0, stream>>>(
            hgr, 0.f, (size_t)G * 256);
        scatter_rows_b<<<N, 256, 0, stream>>>(xh, nullptr, aedge, batch, hgr, N);
        for (int c0 = 0; c0 < G; c0 += McG) {
            int Ms = G - c0 < McG ? G - c0 : McG;
            int gx = cdiv(Ms, 128);
            mgemm<1, 0, 0><<<dim3(gx, 2), 256, 0, stream>>>(Ms, 256, 256,
                hgr + (size_t)c0 * 256, 256, nullptr, nullptr, nullptr,
                pk_mol, mol_bias, nullptr, cbuf, nullptr, 256, NIL);
            mgemm<4, 0, 0><<<dim3(gx, 6), 256, 0, stream>>>(Ms, 512, 512,
                cbuf, 256, nullptr, nullptr, outg + (size_t)c0 * 256,
                pk_gru_s[3], bi3, bh3, Sbuf, nullptr, 768, NIL);
            mgemm<1, 0, 0><<<dim3(gx, 2), 256, 0, stream>>>(Ms, 256, 256,
                outg + (size_t)c0 * 256, 256, nullptr, nullptr, nullptr,
                pk_gru_hn[3], bh3 + 512, nullptr, hnbuf, nullptr, 256, NIL);
            gru_combine_k<false><<<Ms, 256, 0, stream>>>(Sbuf, hnbuf,
                outg + (size_t)c0 * 256, nullptr, Ms);
        }
    }

    // ---- heads ----
    int gG = cdiv(G, 128);
    mgemm<1, 0, 0><<<dim3(gG, 2), 256, 0, stream>>>(G, 256, 256, outg, 256,
        nullptr, nullptr, nullptr, pk_lin2, lin2_b, nullptr,
        fbufA, nullptr, 512, NIL);
    mgemm<1, 3, 0><<<dim3(gG, 2), 256, 0, stream>>>(G, 224, 200, mol_feats, 200,
        nullptr, nullptr, nullptr, pk_fcm0, fcm0_b, nullptr,
        hm1, nullptr, 256, NIL);
    mgemm<1, 3, 0><<<dim3(gG, 2), 256, 0, stream>>>(G, 256, 256, hm1, 256,
        nullptr, nullptr, nullptr, pk_fcm1, fcm1_b, nullptr,
        hm2, nullptr, 256, NIL);
    mgemm<1, 3, 0><<<dim3(gG, 2), 256, 0, stream>>>(G, 256, 256, hm2, 256,
        nullptr, nullptr, nullptr, pk_fcm2, fcm2_b, nullptr,
        fbufA + 256, nullptr, 512, NIL);
    mgemm<1, 3, 0><<<dim3(gG, 4), 256, 0, stream>>>(G, 512, 512, fbufA, 512,
        nullptr, nullptr, nullptr, pk_fc0, fc0_b, nullptr,
        fbufB, nullptr, 512, NIL);
    mgemm<1, 3, 0><<<dim3(gG, 4), 256, 0, stream>>>(G, 512, 512, fbufB, 512,
        nullptr, nullptr, nullptr, pk_fc1, fc1_b, nullptr,
        fbufC, nullptr, 512, NIL);
    mgemm<1, 3, 0><<<dim3(gG, 4), 256, 0, stream>>>(G, 512, 512, fbufC, 512,
        nullptr, nullptr, nullptr, pk_fc2, fc2_b, nullptr,
        fbufB, nullptr, 512, NIL);
    mgemm<1, 3, 0><<<dim3(gG, 1), 256, 0, stream>>>(G, 512, 512, fbufB, 512,
        nullptr, nullptr, nullptr, pk_fc3, fc3_b, nullptr,
        f128, nullptr, 128, NIL);
    fc4_k<<<cdiv(G, 4), 256, 0, stream>>>(f128, fc4_w, fc4_b, out_final, G);
}

// Round 6
// 6627.650 us; speedup vs baseline: 2.4871x; 1.4498x over previous
//
#include <hip/hip_runtime.h>
#include <hip/hip_bf16.h>
#include <math.h>

// ---------------------------------------------------------------------------
// AttentiveFP forward, MI355X. Round 6: split-bf16 MFMA GEMMs + fully fused
// GRU (gates+hn in one GEMM, combine in epilogue) + zero-block MFMA skips.
// ---------------------------------------------------------------------------

typedef unsigned short u16;
typedef u16 u16x8 __attribute__((ext_vector_type(8)));
typedef short s16x8 __attribute__((ext_vector_type(8)));
typedef float f32x4 __attribute__((ext_vector_type(4)));

__device__ __forceinline__ float u2f(u16 u) { return __uint_as_float(((unsigned)u) << 16); }
__device__ __forceinline__ u16 f2u(float f) {
    return __builtin_bit_cast(u16, __float2bfloat16(f));  // RTN
}

#define NEGS 0.01f

__device__ __forceinline__ unsigned fkey(float f) {
    unsigned u = __float_as_uint(f);
    return (u & 0x80000000u) ? ~u : (u | 0x80000000u);
}
__device__ __forceinline__ float funkey(unsigned k) {
    return (k & 0x80000000u) ? __uint_as_float(k ^ 0x80000000u) : __uint_as_float(~k);
}
#define KEY_NEG_INF 0x007FFFFFu

static inline int cdiv(int a, int b) { return (a + b - 1) / b; }

// ---------------- utility kernels ----------------
__global__ void fill_f32(float* p, float v, size_t n) {
    size_t i = (size_t)blockIdx.x * 256 + threadIdx.x;
    if (i < n) p[i] = v;
}
__global__ void fill_u32(unsigned* p, unsigned v, int n) {
    int i = blockIdx.x * 256 + threadIdx.x;
    if (i < n) p[i] = v;
}
__global__ void relu_inplace(float* p, size_t n) {
    size_t i = (size_t)blockIdx.x * 256 + threadIdx.x;
    if (i < n) p[i] = fmaxf(p[i], 0.f);
}
__global__ void copy_f2b(const float* s, u16* d, size_t n) {
    size_t i = (size_t)blockIdx.x * 256 + threadIdx.x;
    if (i < n) d[i] = f2u(s[i]);
}
__global__ void copy_ff(const float* s, float* d, size_t n) {
    size_t i = (size_t)blockIdx.x * 256 + threadIdx.x;
    if (i < n) d[i] = s[i];
}
__global__ void matvecT_k(const float* W, const float* a, float* v, int K, int Jout) {
    int j = blockIdx.x * 256 + threadIdx.x;
    if (j >= Jout) return;
    float s = 0.f;
    for (int k = 0; k < K; k++) s += W[(size_t)k * Jout + j] * a[k];
    v[j] = s;
}
__global__ void edge_add_lrelu(float* elog, const float* r, const int* dsti, int E) {
    int i = blockIdx.x * 256 + threadIdx.x;
    if (i < E) {
        float v = elog[i] + r[dsti[i]];
        elog[i] = v > 0.f ? v : NEGS * v;
    }
}
__global__ void pair_logit(float* elog, const float* s, const float* d,
                           const int* srci, const int* dsti, int E) {
    int i = blockIdx.x * 256 + threadIdx.x;
    if (i < E) {
        float v = s[srci[i]] + d[dsti[i]];
        elog[i] = v > 0.f ? v : NEGS * v;
    }
}
__global__ void node_logit(float* nlog, const float* asrc, const float* wg,
                           const int* batch, int N) {
    int i = blockIdx.x * 256 + threadIdx.x;
    if (i < N) {
        float v = asrc[i] + wg[batch[i]];
        nlog[i] = v > 0.f ? v : NEGS * v;
    }
}
__global__ void seg_max_k(const float* logit, const int* idx, unsigned* key, int n) {
    int i = blockIdx.x * 256 + threadIdx.x;
    if (i < n) atomicMax(&key[idx[i]], fkey(logit[i]));
}
__global__ void seg_exp_k(const float* logit, const int* idx, const unsigned* key,
                          float* ex, float* sum, int n) {
    int i = blockIdx.x * 256 + threadIdx.x;
    if (i < n) {
        float e = expf(logit[i] - funkey(key[idx[i]]));
        ex[i] = e;
        atomicAdd(&sum[idx[i]], e);
    }
}
__global__ void seg_div_k(const float* ex, const int* idx, const float* sum,
                          float* a, int n) {
    int i = blockIdx.x * 256 + threadIdx.x;
    if (i < n) a[i] = ex[i] / (sum[idx[i]] + 1e-16f);
}
__global__ void scatter_rows_b(const u16* V, const int* gsrc, const float* sc,
                               const int* gdst, float* dst, int M) {
    int r = blockIdx.x;
    if (r >= M) return;
    int c = threadIdx.x;
    int vr = gsrc ? gsrc[r] : r;
    float v = u2f(V[(size_t)vr * 256 + c]);
    if (sc) v *= sc[r];
    atomicAdd(&dst[(size_t)gdst[r] * 256 + c], v);
}
__global__ void rowdot2_b(const u16* X, const float* v1, const float* v2,
                          float* o1, float* o2, int M) {
    int r = blockIdx.x * 4 + (threadIdx.x >> 6);
    int lane = threadIdx.x & 63;
    if (r >= M) return;
    const u16* row = X + (size_t)r * 256 + lane * 4;
    float p1 = 0.f, p2 = 0.f;
#pragma unroll
    for (int q = 0; q < 4; q++) {
        float xv = u2f(row[q]);
        p1 += xv * v1[lane * 4 + q];
        if (v2) p2 += xv * v2[lane * 4 + q];
    }
    for (int off = 32; off; off >>= 1) {
        p1 += __shfl_down(p1, off);
        if (v2) p2 += __shfl_down(p2, off);
    }
    if (lane == 0) {
        o1[r] = p1;
        if (v2) o2[r] = p2;
    }
}
__global__ void rowdot_f(const float* X, const float* v1, float* o1, int M) {
    int r = blockIdx.x * 4 + (threadIdx.x >> 6);
    int lane = threadIdx.x & 63;
    if (r >= M) return;
    float4 a = ((const float4*)(X + (size_t)r * 256))[lane];
    float4 b = ((const float4*)v1)[lane];
    float p1 = a.x * b.x + a.y * b.y + a.z * b.z + a.w * b.w;
    for (int off = 32; off; off >>= 1) p1 += __shfl_down(p1, off);
    if (lane == 0) o1[r] = p1;
}
__global__ void fc4_k(const float* X, const float* w, const float* b, float* out, int G) {
    int g = blockIdx.x * 4 + (threadIdx.x >> 6);
    int lane = threadIdx.x & 63;
    if (g >= G) return;
    float2 xv = ((const float2*)(X + (size_t)g * 128))[lane];
    float2 wv = ((const float2*)w)[lane];
    float p = xv.x * wv.x + xv.y * wv.y;
    for (int off = 32; off; off >>= 1) p += __shfl_down(p, off);
    if (lane == 0) out[g] = p + b[0];
}

// ---------------- weight pre-pack (hi||lo) into MFMA operand order ----------
// chunk c: n = nblk*128+((c>>6)&7)*16+(c&15), k = kiter*32+((c>>4)&3)*8+j
__global__ void pack_w(const float* s1, const float* s2, int K1, int Ksrc,
                       int Nout, int Kp, u16* dst) {
    int idx = blockIdx.x * 256 + threadIdx.x;
    int kiters = Kp >> 5;
    int total = (Nout >> 7) * kiters * 512;
    if (idx >= total) return;
    int c = idx & 511;
    int rest = idx >> 9;
    int ki = rest % kiters, nb = rest / kiters;
    int n = (nb << 7) + (((c >> 6) & 7) << 4) + (c & 15);
    int k0 = (ki << 5) + (((c >> 4) & 3) << 3);
    u16x8 vh, vl;
#pragma unroll
    for (int j = 0; j < 8; j++) {
        int k = k0 + j;
        float f = 0.f;
        if (k < K1) f = s1[(size_t)n * K1 + k];
        else if (k < Ksrc) f = s2[(size_t)n * (Ksrc - K1) + (k - K1)];
        u16 h = f2u(f);
        vh[j] = h;
        vl[j] = f2u(f - u2f(h));
    }
    ((u16x8*)dst)[idx] = vh;
    ((u16x8*)dst)[idx + total] = vl;
}
// GRU fused weights: W'[1024,512], columns interleaved per 16-ch group
// [r16|z16|n16|hn16]; rows r/z/n = [wi|wh], hn = [0|wh_n].
__global__ void pack_gru_w(const float* wi, const float* wh, u16* dst) {
    int idx = blockIdx.x * 256 + threadIdx.x;
    const int total = 8 * 16 * 512;
    if (idx >= total) return;
    int c = idx & 511, rest = idx >> 9;
    int ki = rest & 15, nb = rest >> 4;
    int n = (nb << 7) + (((c >> 6) & 7) << 4) + (c & 15);
    int k0 = (ki << 5) + (((c >> 4) & 3) << 3);
    int grp = n >> 6, sub = (n >> 4) & 3, ch = grp * 16 + (n & 15);
    u16x8 vh, vl;
#pragma unroll
    for (int j = 0; j < 8; j++) {
        int k = k0 + j;
        float f;
        if (sub < 3) {
            int srow = sub * 256 + ch;
            f = (k < 256) ? wi[(size_t)srow * 256 + k]
                          : wh[(size_t)srow * 256 + (k - 256)];
        } else {
            f = (k < 256) ? 0.f : wh[(size_t)(512 + ch) * 256 + (k - 256)];
        }
        u16 h = f2u(f);
        vh[j] = h;
        vl[j] = f2u(f - u2f(h));
    }
    ((u16x8*)dst)[idx] = vh;
    ((u16x8*)dst)[idx + total] = vl;
}
__global__ void pack_gru_b(const float* bi, const float* bh, float* bp) {
    int n = blockIdx.x * 256 + threadIdx.x;
    if (n >= 1024) return;
    int grp = n >> 6, sub = (n >> 4) & 3, ch = grp * 16 + (n & 15);
    float v;
    if (sub == 0) v = bi[ch] + bh[ch];
    else if (sub == 1) v = bi[256 + ch] + bh[256 + ch];
    else if (sub == 2) v = bi[512 + ch] + bh[512 + ch];
    else v = bh[512 + ch];
    bp[n] = v;
}

// ---------------- split-bf16 loaders ----------------
struct p8 { u16x8 hi, lo; };
__device__ __forceinline__ u16x8 zero8() {
    u16x8 z;
#pragma unroll
    for (int j = 0; j < 8; j++) z[j] = 0;
    return z;
}
__device__ __forceinline__ p8 sp_zero() { p8 r; r.hi = zero8(); r.lo = zero8(); return r; }
__device__ __forceinline__ p8 sp_b(const u16* p) {
    p8 r;
    r.hi = *(const u16x8*)p;
    r.lo = zero8();
    return r;
}
__device__ __forceinline__ p8 sp_f(const float* p) {
    p8 r;
#pragma unroll
    for (int j = 0; j < 8; j++) {
        float x = p[j];
        u16 h = f2u(x);
        r.hi[j] = h;
        r.lo[j] = f2u(x - u2f(h));
    }
    return r;
}
__device__ __forceinline__ p8 sp_eluf(const float* p) {
    p8 r;
#pragma unroll
    for (int j = 0; j < 8; j++) {
        float x = p[j];
        float e = x > 0.f ? x : expm1f(x);
        u16 h = f2u(e);
        r.hi[j] = h;
        r.lo[j] = f2u(e - u2f(h));
    }
    return r;
}
// ALD: 1 f32 Af(lda) pad k>=Ksrc; 2 [xh[gidx] bf16 | edge_attr f32(16) | 0];
//      3 [elu(f32 Af) | bf16 Ab]; 4 [elu(f32 Af) | f32 X2f]
template <int ALD>
__device__ __forceinline__ p8 ldA(bool valid, int k, int Ksrc, const u16* ab,
                                  const float* af, const float* x2) {
    if (!valid) return sp_zero();
    if (ALD == 1) {
        if (k >= Ksrc) return sp_zero();
        return sp_f(af + k);
    }
    if (ALD == 2) {
        if (k < 256) return sp_b(ab + k);
        if (k < 272) return sp_f(x2 + (k - 256));
        return sp_zero();
    }
    if (ALD == 3) {
        if (k < 256) return sp_eluf(af + k);
        return sp_b(ab + (k - 256));
    }
    if (k < 256) return sp_eluf(af + k);
    return sp_f(x2 + (k - 256));
}
// is A_lo exactly zero for this 32-wide k-iter?
template <int ALD>
__device__ __forceinline__ bool lo_zero(int ki) {
    if (ALD == 2) return ki < 8;
    if (ALD == 3) return ki >= 8;
    return false;
}
template <int ACT>
__device__ __forceinline__ float actf(float v) {
    if (ACT == 1) return v > 0.f ? v : NEGS * v;
    if (ACT == 3) return v / (1.f + expf(-v));
    return v;
}

// ---------------- generic split-bf16 MFMA GEMM ----------------
// EPI: 0 f32 store; 1 bf16 store; 2 DOTV; 3 SCAT
template <int ALD, int ACT, int EPI>
__global__ __launch_bounds__(256, 2) void mgemm(
    int M, int Kp, int Ksrc,
    const float* Af, int lda, const u16* Ab,
    const int* gidx, const float* X2f, const u16* Wp,
    const float* b1,
    float* Cf, u16* Cb, int ldc,
    const float* attv, float* dotout,
    const int* didx, const float* escale, float* scat) {
    __shared__ u16x8 lsAh[512];
    __shared__ u16x8 lsAl[512];
    __shared__ u16x8 lsWh[512];
    __shared__ u16x8 lsWl[512];
    const int t = threadIdx.x;
    const int m0 = blockIdx.x * 128;
    const int nb = blockIdx.y;
    const int kiters = Kp >> 5;
    const int r0 = ((t >> 6) << 4) | (t & 15);
    const int kq = ((t >> 4) & 3) << 3;
    const int mA[2] = {m0 + r0, m0 + r0 + 64};
    const u16* abr[2];
    const float* afr[2];
    const float* x2r[2];
    bool val[2];
#pragma unroll
    for (int h = 0; h < 2; h++) {
        int m = mA[h];
        val[h] = (m < M);
        int ms = val[h] ? m : 0;
        abr[h] = nullptr; afr[h] = nullptr; x2r[h] = nullptr;
        if (ALD == 1) {
            afr[h] = Af + (size_t)ms * lda;
        } else if (ALD == 2) {
            abr[h] = Ab + (size_t)gidx[ms] * 256;
            x2r[h] = X2f + (size_t)ms * 16;
        } else if (ALD == 3) {
            afr[h] = Af + (size_t)ms * 256;
            abr[h] = Ab + (size_t)ms * 256;
        } else {
            afr[h] = Af + (size_t)ms * 256;
            x2r[h] = X2f + (size_t)ms * 256;
        }
    }
    const int wave = t >> 6, lane = t & 63;
    const int wm = (wave >> 1) << 6, wn = (wave & 1) << 6;
    f32x4 acc[4][4];
#pragma unroll
    for (int i = 0; i < 4; i++)
#pragma unroll
        for (int j = 0; j < 4; j++) {
            acc[i][j][0] = 0.f; acc[i][j][1] = 0.f; acc[i][j][2] = 0.f; acc[i][j][3] = 0.f;
        }
    const u16x8* wh0 = (const u16x8*)Wp + ((size_t)nb * kiters << 9);
    const u16x8* wl0 = wh0 + ((size_t)gridDim.y * kiters << 9);
    for (int ki = 0; ki < kiters; ki++) {
        int kb = (ki << 5) + kq;
        p8 a0 = ldA<ALD>(val[0], kb, Ksrc, abr[0], afr[0], x2r[0]);
        p8 a1 = ldA<ALD>(val[1], kb, Ksrc, abr[1], afr[1], x2r[1]);
        lsAh[t] = a0.hi; lsAl[t] = a0.lo;
        lsAh[t + 256] = a1.hi; lsAl[t + 256] = a1.lo;
        const u16x8* wsh = wh0 + ((size_t)ki << 9);
        const u16x8* wsl = wl0 + ((size_t)ki << 9);
        lsWh[t] = wsh[t]; lsWh[t + 256] = wsh[t + 256];
        lsWl[t] = wsl[t]; lsWl[t + 256] = wsl[t + 256];
        __syncthreads();
        s16x8 ah[4], al[4], wh[4], wl[4];
#pragma unroll
        for (int f = 0; f < 4; f++) {
            int ai = ((wm >> 4) + f) * 64 + lane;
            int wi = ((wn >> 4) + f) * 64 + lane;
            ah[f] = __builtin_bit_cast(s16x8, lsAh[ai]);
            al[f] = __builtin_bit_cast(s16x8, lsAl[ai]);
            wh[f] = __builtin_bit_cast(s16x8, lsWh[wi]);
            wl[f] = __builtin_bit_cast(s16x8, lsWl[wi]);
        }
        bool skip_lh = lo_zero<ALD>(ki);
#pragma unroll
        for (int fi = 0; fi < 4; fi++)
#pragma unroll
            for (int fj = 0; fj < 4; fj++) {
                acc[fi][fj] = __builtin_amdgcn_mfma_f32_16x16x32_bf16(
                    ah[fi], wh[fj], acc[fi][fj], 0, 0, 0);
                if (!skip_lh)
                    acc[fi][fj] = __builtin_amdgcn_mfma_f32_16x16x32_bf16(
                        al[fi], wh[fj], acc[fi][fj], 0, 0, 0);
                acc[fi][fj] = __builtin_amdgcn_mfma_f32_16x16x32_bf16(
                    ah[fi], wl[fj], acc[fi][fj], 0, 0, 0);
            }
        __syncthreads();
    }
    const int col = lane & 15, quad = lane >> 4;
    const int n_base = nb * 128 + wn;
    if (EPI == 2) {
        float dp[4][4] = {};
#pragma unroll
        for (int fi = 0; fi < 4; fi++)
#pragma unroll
            for (int fj = 0; fj < 4; fj++) {
                int nn = n_base + fj * 16 + col;
                float av = attv[nn];
#pragma unroll
                for (int r = 0; r < 4; r++) dp[fi][r] += actf<ACT>(acc[fi][fj][r]) * av;
            }
#pragma unroll
        for (int fi = 0; fi < 4; fi++)
#pragma unroll
            for (int r = 0; r < 4; r++) {
                float p = dp[fi][r];
                p += __shfl_down(p, 8);
                p += __shfl_down(p, 4);
                p += __shfl_down(p, 2);
                p += __shfl_down(p, 1);
                int mm = m0 + wm + fi * 16 + quad * 4 + r;
                if (col == 0 && mm < M) atomicAdd(dotout + mm, p);
            }
    } else if (EPI == 3) {
#pragma unroll
        for (int fi = 0; fi < 4; fi++)
#pragma unroll
            for (int r = 0; r < 4; r++) {
                int mm = m0 + wm + fi * 16 + quad * 4 + r;
                if (mm >= M) continue;
                int d = didx[mm];
                float s = escale[mm];
                float* rowp = scat + (size_t)d * 256;
#pragma unroll
                for (int fj = 0; fj < 4; fj++) {
                    int nn = n_base + fj * 16 + col;
                    atomicAdd(rowp + nn, actf<ACT>(acc[fi][fj][r]) * s);
                }
            }
    } else {
#pragma unroll
        for (int fj = 0; fj < 4; fj++) {
            int nn = n_base + fj * 16 + col;
            float bb = b1 ? b1[nn] : 0.f;
#pragma unroll
            for (int fi = 0; fi < 4; fi++)
#pragma unroll
                for (int r = 0; r < 4; r++) {
                    int mm = m0 + wm + fi * 16 + quad * 4 + r;
                    if (mm >= M) continue;
                    float v = actf<ACT>(acc[fi][fj][r] + bb);
                    if (EPI == 1) Cb[(size_t)mm * ldc + nn] = f2u(v);
                    else Cf[(size_t)mm * ldc + nn] = v;
                }
        }
    }
}

// ---------------- fused GRU GEMM: [elu(cbuf)|h] @ W'[1024,512]^T ------------
// grid (M/128, 8). Columns interleaved [r|z|n|hn] per 16ch. Epilogue does the
// full GRU combine and writes h_new (fp32) to `of` (stride 256).
// HB: h_old is bf16 (hb) else fp32 (hf). ALD 3: h-half bf16; ALD 4: f32.
template <int ALD, bool HB>
__global__ __launch_bounds__(256, 2) void mgemm_gru(
    int M,
    const float* Af, const u16* Ab, const float* X2f,
    const u16* Wp, const float* bp,
    const u16* hb, const float* hf, float* of) {
    __shared__ u16x8 lsAh[512];
    __shared__ u16x8 lsAl[512];
    __shared__ u16x8 lsWh[512];
    __shared__ u16x8 lsWl[512];
    const int t = threadIdx.x;
    const int m0 = blockIdx.x * 128;
    const int nb = blockIdx.y;  // 0..7
    const int r0 = ((t >> 6) << 4) | (t & 15);
    const int kq = ((t >> 4) & 3) << 3;
    const int mA[2] = {m0 + r0, m0 + r0 + 64};
    const u16* abr[2];
    const float* afr[2];
    const float* x2r[2];
    bool val[2];
#pragma unroll
    for (int h = 0; h < 2; h++) {
        int m = mA[h];
        val[h] = (m < M);
        int ms = val[h] ? m : 0;
        abr[h] = nullptr; x2r[h] = nullptr;
        afr[h] = Af + (size_t)ms * 256;
        if (ALD == 3) abr[h] = Ab + (size_t)ms * 256;
        else x2r[h] = X2f + (size_t)ms * 256;
    }
    const int wave = t >> 6, lane = t & 63;
    const int wm = (wave >> 1) << 6, wn = (wave & 1) << 6;
    f32x4 acc[4][4];
#pragma unroll
    for (int i = 0; i < 4; i++)
#pragma unroll
        for (int j = 0; j < 4; j++) {
            acc[i][j][0] = 0.f; acc[i][j][1] = 0.f; acc[i][j][2] = 0.f; acc[i][j][3] = 0.f;
        }
    const u16x8* wh0 = (const u16x8*)Wp + ((size_t)nb * 16 << 9);
    const u16x8* wl0 = (const u16x8*)Wp + (size_t)(8 * 16 * 512) + ((size_t)nb * 16 << 9);
    for (int ki = 0; ki < 16; ki++) {
        int kb = (ki << 5) + kq;
        p8 a0 = ldA<ALD>(val[0], kb, 512, abr[0], afr[0], x2r[0]);
        p8 a1 = ldA<ALD>(val[1], kb, 512, abr[1], afr[1], x2r[1]);
        lsAh[t] = a0.hi; lsAl[t] = a0.lo;
        lsAh[t + 256] = a1.hi; lsAl[t + 256] = a1.lo;
        const u16x8* wsh = wh0 + ((size_t)ki << 9);
        const u16x8* wsl = wl0 + ((size_t)ki << 9);
        lsWh[t] = wsh[t]; lsWh[t + 256] = wsh[t + 256];
        lsWl[t] = wsl[t]; lsWl[t + 256] = wsl[t + 256];
        __syncthreads();
        s16x8 ah[4], al[4], wh[4], wl[4];
#pragma unroll
        for (int f = 0; f < 4; f++) {
            int ai = ((wm >> 4) + f) * 64 + lane;
            int wi = ((wn >> 4) + f) * 64 + lane;
            ah[f] = __builtin_bit_cast(s16x8, lsAh[ai]);
            al[f] = __builtin_bit_cast(s16x8, lsAl[ai]);
            wh[f] = __builtin_bit_cast(s16x8, lsWh[wi]);
            wl[f] = __builtin_bit_cast(s16x8, lsWl[wi]);
        }
        bool skip_lh = lo_zero<ALD>(ki);
        bool hn_zero = (ki < 8);  // hn-columns (fj==3) have W'==0 for k<256
#pragma unroll
        for (int fi = 0; fi < 4; fi++)
#pragma unroll
            for (int fj = 0; fj < 4; fj++) {
                if (fj == 3 && hn_zero) continue;
                acc[fi][fj] = __builtin_amdgcn_mfma_f32_16x16x32_bf16(
                    ah[fi], wh[fj], acc[fi][fj], 0, 0, 0);
                if (!skip_lh)
                    acc[fi][fj] = __builtin_amdgcn_mfma_f32_16x16x32_bf16(
                        al[fi], wh[fj], acc[fi][fj], 0, 0, 0);
                acc[fi][fj] = __builtin_amdgcn_mfma_f32_16x16x32_bf16(
                    ah[fi], wl[fj], acc[fi][fj], 0, 0, 0);
            }
        __syncthreads();
    }
    const int col = lane & 15, quad = lane >> 4;
    const int nbase = nb * 128 + wn;
    float br = bp[nbase + col];
    float bz = bp[nbase + 16 + col];
    float bn = bp[nbase + 32 + col];
    float bhn = bp[nbase + 48 + col];
    int ch = (nb * 2 + (wn >> 6)) * 16 + col;  // 0..255
#pragma unroll
    for (int fi = 0; fi < 4; fi++)
#pragma unroll
        for (int r = 0; r < 4; r++) {
            int m = m0 + wm + fi * 16 + quad * 4 + r;
            if (m >= M) continue;
            float rs = acc[fi][0][r] + br;
            float zs = acc[fi][1][r] + bz;
            float nsv = acc[fi][2][r] + bn;
            float hnv = acc[fi][3][r] + bhn;
            float rr = 1.f / (1.f + expf(-rs));
            float zz = 1.f / (1.f + expf(-zs));
            float nn = tanhf(nsv - hnv + rr * hnv);
            float ho = HB ? u2f(hb[(size_t)m * 256 + ch]) : hf[(size_t)m * 256 + ch];
            of[(size_t)m * 256 + ch] = fmaxf((1.f - zz) * nn + zz * ho, 0.f);
        }
}

extern "C" void kernel_launch(void* const* d_in, const int* in_sizes, int n_in,
                              void* d_out, int out_size, void* d_ws, size_t ws_size,
                              hipStream_t stream) {
    const float* x = (const float*)d_in[0];
    const float* edge_attr = (const float*)d_in[1];
    const float* mol_feats = (const float*)d_in[2];
    const float* lin1_w = (const float*)d_in[3];
    const float* lin1_b = (const float*)d_in[4];
    const float* gate_lin1_w = (const float*)d_in[5];
    const float* gate_lin2_w = (const float*)d_in[6];
    const float* gate_att_l = (const float*)d_in[7];
    const float* gate_att_r = (const float*)d_in[8];
    const float* gate_bias = (const float*)d_in[9];
    const float* grus_wi = (const float*)d_in[10];
    const float* grus_wh = (const float*)d_in[11];
    const float* grus_bi = (const float*)d_in[12];
    const float* grus_bh = (const float*)d_in[13];
    const float* atom_w = (const float*)d_in[14];
    const float* atom_att_src = (const float*)d_in[15];
    const float* atom_att_dst = (const float*)d_in[16];
    const float* atom_bias = (const float*)d_in[17];
    const float* mol_w = (const float*)d_in[18];
    const float* mol_att_src = (const float*)d_in[19];
    const float* mol_att_dst = (const float*)d_in[20];
    const float* mol_bias = (const float*)d_in[21];
    const float* lin2_w = (const float*)d_in[22];
    const float* lin2_b = (const float*)d_in[23];
    const float* fcm0_w = (const float*)d_in[24];
    const float* fcm0_b = (const float*)d_in[25];
    const float* fcm1_w = (const float*)d_in[26];
    const float* fcm1_b = (const float*)d_in[27];
    const float* fcm2_w = (const float*)d_in[28];
    const float* fcm2_b = (const float*)d_in[29];
    const float* fc0_w = (const float*)d_in[30];
    const float* fc0_b = (const float*)d_in[31];
    const float* fc1_w = (const float*)d_in[32];
    const float* fc1_b = (const float*)d_in[33];
    const float* fc2_w = (const float*)d_in[34];
    const float* fc2_b = (const float*)d_in[35];
    const float* fc3_w = (const float*)d_in[36];
    const float* fc3_b = (const float*)d_in[37];
    const float* fc4_w = (const float*)d_in[38];
    const float* fc4_b = (const float*)d_in[39];
    const int* edge_index = (const int*)d_in[40];
    const int* batch = (const int*)d_in[41];
    float* out_final = (float*)d_out;

    const int N = in_sizes[0] / 64;
    const int E = in_sizes[1] / 16;
    const int G = in_sizes[2] / 200;
    const int* srcE = edge_index;
    const int* dstE = edge_index + E;

    // ---- workspace layout ----
    char* base = (char*)d_ws;
    size_t off = 0;
    auto alloc = [&](size_t bytes) -> char* {
        char* p = base + off;
        off += (bytes + 255) & ~(size_t)255;
        return p;
    };
    u16* xh = (u16*)alloc((size_t)N * 256 * 2);
    float* hagg = (float*)alloc((size_t)N * 256 * 4);   // scatter tgt / h_new / heads
    float* outg = (float*)alloc((size_t)G * 256 * 4);
    float* hgr = (float*)alloc((size_t)G * 256 * 4);
    float* elog = (float*)alloc((size_t)E * 4);
    float* eexp = (float*)alloc((size_t)E * 4);
    float* aedge = (float*)alloc((size_t)E * 4);
    unsigned* nkey = (unsigned*)alloc((size_t)N * 4);
    float* nsum = (float*)alloc((size_t)N * 4);
    float* ns1 = (float*)alloc((size_t)N * 4);
    float* ns2 = (float*)alloc((size_t)N * 4);
    unsigned* gkey = (unsigned*)alloc((size_t)G * 4);
    float* gsum = (float*)alloc((size_t)G * 4);
    float* wgb = (float*)alloc((size_t)G * 4);
    float* vbuf = (float*)alloc(1024 * 4);
    // packed weights (hi||lo)
    u16* pk_lin1 = (u16*)alloc(256 * 64 * 2 * 2);
    u16* pk_g1 = (u16*)alloc(256 * 288 * 2 * 2);
    u16* pk_g2 = (u16*)alloc(256 * 256 * 2 * 2);
    u16* pk_gruF[4];
    float* bp_gru[4];
    for (int l = 0; l < 4; l++) {
        pk_gruF[l] = (u16*)alloc(1024 * 512 * 2 * 2);
        bp_gru[l] = (float*)alloc(1024 * 4);
    }
    u16* pk_atom[2];
    for (int l = 0; l < 2; l++) pk_atom[l] = (u16*)alloc(256 * 256 * 2 * 2);
    u16* pk_mol = (u16*)alloc(256 * 256 * 2 * 2);
    u16* pk_lin2 = (u16*)alloc(256 * 256 * 2 * 2);
    u16* pk_fcm0 = (u16*)alloc(256 * 224 * 2 * 2);
    u16* pk_fcm1 = (u16*)alloc(256 * 256 * 2 * 2);
    u16* pk_fcm2 = (u16*)alloc(256 * 256 * 2 * 2);
    u16* pk_fc0 = (u16*)alloc(512 * 512 * 2 * 2);
    u16* pk_fc1 = (u16*)alloc(512 * 512 * 2 * 2);
    u16* pk_fc2 = (u16*)alloc(512 * 512 * 2 * 2);
    u16* pk_fc3 = (u16*)alloc(128 * 512 * 2 * 2);
    size_t fixed_bytes = off;
    if (fixed_bytes + (size_t)2 * 1024 * 1024 > ws_size) {
        fill_f32<<<cdiv(out_size, 256), 256, 0, stream>>>(out_final, (float)ws_size,
                                                          (size_t)out_size);
        return;
    }
    size_t avail = ws_size - fixed_bytes;
    float* cbuf = (float*)(base + fixed_bytes);
    int Mc = (int)((avail / 1024) & ~(size_t)127);  // rows of cbuf fp32 [Mc,256]
    if (Mc > N) Mc = N;
    if (Mc < 128) Mc = 128;
    // heads alias into hagg (dead by then)
    float* fbufA = hagg;
    float* fbufB = fbufA + (size_t)G * 512;
    float* fbufC = fbufB + (size_t)G * 512;
    float* f128 = fbufC + (size_t)G * 512;
    float* hm1 = f128 + (size_t)G * 128;
    float* hm2 = hm1 + (size_t)G * 256;

    // ---- pack all weights ----
    auto pack = [&](const float* s1, const float* s2, int K1, int Ksrc, int Nout,
                    int Kp, u16* dst) {
        int total = (Nout >> 7) * (Kp >> 5) * 512;
        pack_w<<<cdiv(total, 256), 256, 0, stream>>>(s1, s2, K1, Ksrc, Nout, Kp, dst);
    };
    pack(lin1_w, nullptr, 64, 64, 256, 64, pk_lin1);
    pack(gate_lin1_w, nullptr, 272, 272, 256, 288, pk_g1);
    pack(gate_lin2_w, nullptr, 256, 256, 256, 256, pk_g2);
    for (int l = 0; l < 4; l++) {
        pack_gru_w<<<cdiv(8 * 16 * 512, 256), 256, 0, stream>>>(
            grus_wi + (size_t)l * 768 * 256, grus_wh + (size_t)l * 768 * 256,
            pk_gruF[l]);
        pack_gru_b<<<4, 256, 0, stream>>>(grus_bi + (size_t)l * 768,
                                          grus_bh + (size_t)l * 768, bp_gru[l]);
    }
    for (int l = 0; l < 2; l++)
        pack(atom_w + (size_t)l * 256 * 256, nullptr, 256, 256, 256, 256, pk_atom[l]);
    pack(mol_w, nullptr, 256, 256, 256, 256, pk_mol);
    pack(lin2_w, nullptr, 256, 256, 256, 256, pk_lin2);
    pack(fcm0_w, nullptr, 200, 200, 256, 224, pk_fcm0);
    pack(fcm1_w, nullptr, 256, 256, 256, 256, pk_fcm1);
    pack(fcm2_w, nullptr, 256, 256, 256, 256, pk_fcm2);
    pack(fc0_w, nullptr, 512, 512, 512, 512, pk_fc0);
    pack(fc1_w, nullptr, 512, 512, 512, 512, pk_fc1);
    pack(fc2_w, nullptr, 512, 512, 512, 512, pk_fc2);
    pack(fc3_w, nullptr, 512, 512, 128, 512, pk_fc3);

#define NIL nullptr, nullptr, nullptr, nullptr, nullptr

    // node GRU layer: hagg --(Wpre,bpre)--> cbuf --fused GRU--> hagg; copy->xh
    auto node_gru = [&](int l, const u16* Wpre, const float* bpre) {
        for (int c0 = 0; c0 < N; c0 += Mc) {
            int Ms = N - c0 < Mc ? N - c0 : Mc;
            int gx = cdiv(Ms, 128);
            mgemm<1, 0, 0><<<dim3(gx, 2), 256, 0, stream>>>(Ms, 256, 256,
                hagg + (size_t)c0 * 256, 256, nullptr, nullptr, nullptr,
                Wpre, bpre, cbuf, nullptr, 256, NIL);
            mgemm_gru<3, true><<<dim3(gx, 8), 256, 0, stream>>>(Ms,
                cbuf, xh + (size_t)c0 * 256, nullptr, pk_gruF[l], bp_gru[l],
                xh + (size_t)c0 * 256, nullptr, hagg + (size_t)c0 * 256);
        }
        copy_f2b<<<(int)(((size_t)N * 256 + 255) / 256), 256, 0, stream>>>(
            hagg, xh, (size_t)N * 256);
    };

    // ---- xh = lrelu(x @ lin1_w^T + lin1_b) ----
    mgemm<1, 1, 1><<<dim3(cdiv(N, 128), 2), 256, 0, stream>>>(N, 64, 64,
        x, 64, nullptr, nullptr, nullptr, pk_lin1, lin1_b,
        nullptr, xh, 256, NIL);

    // ---- GATEConv ----
    fill_f32<<<cdiv(E, 256), 256, 0, stream>>>(elog, 0.f, (size_t)E);
    mgemm<2, 1, 2><<<dim3(cdiv(E, 128), 2), 256, 0, stream>>>(E, 288, 272,
        nullptr, 0, xh, srcE, edge_attr, pk_g1, nullptr,
        nullptr, nullptr, 0, gate_att_l, elog, nullptr, nullptr, nullptr);
    rowdot2_b<<<cdiv(N, 4), 256, 0, stream>>>(xh, gate_att_r, nullptr, ns1, nullptr, N);
    edge_add_lrelu<<<cdiv(E, 256), 256, 0, stream>>>(elog, ns1, dstE, E);
    fill_u32<<<cdiv(N, 256), 256, 0, stream>>>(nkey, KEY_NEG_INF, N);
    fill_f32<<<cdiv(N, 256), 256, 0, stream>>>(nsum, 0.f, (size_t)N);
    seg_max_k<<<cdiv(E, 256), 256, 0, stream>>>(elog, dstE, nkey, E);
    seg_exp_k<<<cdiv(E, 256), 256, 0, stream>>>(elog, dstE, nkey, eexp, nsum, E);
    seg_div_k<<<cdiv(E, 256), 256, 0, stream>>>(eexp, dstE, nsum, aedge, E);
    fill_f32<<<(int)(((size_t)N * 256 + 255) / 256), 256, 0, stream>>>(
        hagg, 0.f, (size_t)N * 256);
    mgemm<2, 1, 3><<<dim3(cdiv(E, 128), 2), 256, 0, stream>>>(E, 288, 272,
        nullptr, 0, xh, srcE, edge_attr, pk_g1, nullptr,
        nullptr, nullptr, 0, nullptr, nullptr, dstE, aedge, hagg);
    node_gru(0, pk_g2, gate_bias);

    // ---- GATConv l=0,1 ----
    for (int l = 0; l < 2; l++) {
        const float* aw = atom_w + (size_t)l * 256 * 256;
        matvecT_k<<<1, 256, 0, stream>>>(aw, atom_att_src + (size_t)l * 256, vbuf, 256, 256);
        matvecT_k<<<1, 256, 0, stream>>>(aw, atom_att_dst + (size_t)l * 256, vbuf + 256, 256, 256);
        rowdot2_b<<<cdiv(N, 4), 256, 0, stream>>>(xh, vbuf, vbuf + 256, ns1, ns2, N);
        pair_logit<<<cdiv(E, 256), 256, 0, stream>>>(elog, ns1, ns2, srcE, dstE, E);
        fill_u32<<<cdiv(N, 256), 256, 0, stream>>>(nkey, KEY_NEG_INF, N);
        fill_f32<<<cdiv(N, 256), 256, 0, stream>>>(nsum, 0.f, (size_t)N);
        seg_max_k<<<cdiv(E, 256), 256, 0, stream>>>(elog, dstE, nkey, E);
        seg_exp_k<<<cdiv(E, 256), 256, 0, stream>>>(elog, dstE, nkey, eexp, nsum, E);
        seg_div_k<<<cdiv(E, 256), 256, 0, stream>>>(eexp, dstE, nsum, aedge, E);
        fill_f32<<<(int)(((size_t)N * 256 + 255) / 256), 256, 0, stream>>>(
            hagg, 0.f, (size_t)N * 256);
        scatter_rows_b<<<E, 256, 0, stream>>>(xh, srcE, aedge, dstE, hagg, E);
        node_gru(1 + l, pk_atom[l], atom_bias + (size_t)l * 256);
    }

    // ---- attentive readout ----
    fill_f32<<<(int)(((size_t)G * 256 + 255) / 256), 256, 0, stream>>>(
        outg, 0.f, (size_t)G * 256);
    scatter_rows_b<<<N, 256, 0, stream>>>(xh, nullptr, nullptr, batch, outg, N);
    relu_inplace<<<(int)(((size_t)G * 256 + 255) / 256), 256, 0, stream>>>(
        outg, (size_t)G * 256);
    matvecT_k<<<1, 256, 0, stream>>>(mol_w, mol_att_dst, vbuf, 256, 256);
    matvecT_k<<<1, 256, 0, stream>>>(mol_w, mol_att_src, vbuf + 256, 256, 256);
    rowdot2_b<<<cdiv(N, 4), 256, 0, stream>>>(xh, vbuf + 256, nullptr, ns1, nullptr, N);
    int McG = Mc < G ? Mc : G;
    for (int t = 0; t < 3; t++) {
        rowdot_f<<<cdiv(G, 4), 256, 0, stream>>>(outg, vbuf, wgb, G);
        node_logit<<<cdiv(N, 256), 256, 0, stream>>>(elog, ns1, wgb, batch, N);
        fill_u32<<<cdiv(G, 256), 256, 0, stream>>>(gkey, KEY_NEG_INF, G);
        fill_f32<<<cdiv(G, 256), 256, 0, stream>>>(gsum, 0.f, (size_t)G);
        seg_max_k<<<cdiv(N, 256), 256, 0, stream>>>(elog, batch, gkey, N);
        seg_exp_k<<<cdiv(N, 256), 256, 0, stream>>>(elog, batch, gkey, eexp, gsum, N);
        seg_div_k<<<cdiv(N, 256), 256, 0, stream>>>(eexp, batch, gsum, aedge, N);
        fill_f32<<<(int)(((size_t)G * 256 + 255) / 256), 256, 0, stream>>>(
            hgr, 0.f, (size_t)G * 256);
        scatter_rows_b<<<N, 256, 0, stream>>>(xh, nullptr, aedge, batch, hgr, N);
        for (int c0 = 0; c0 < G; c0 += McG) {
            int Ms = G - c0 < McG ? G - c0 : McG;
            int gx = cdiv(Ms, 128);
            mgemm<1, 0, 0><<<dim3(gx, 2), 256, 0, stream>>>(Ms, 256, 256,
                hgr + (size_t)c0 * 256, 256, nullptr, nullptr, nullptr,
                pk_mol, mol_bias, cbuf, nullptr, 256, NIL);
            mgemm_gru<4, false><<<dim3(gx, 8), 256, 0, stream>>>(Ms,
                cbuf, nullptr, outg + (size_t)c0 * 256, pk_gruF[3], bp_gru[3],
                nullptr, outg + (size_t)c0 * 256, hgr + (size_t)c0 * 256);
        }
        copy_ff<<<(int)(((size_t)G * 256 + 255) / 256), 256, 0, stream>>>(
            hgr, outg, (size_t)G * 256);
    }

    // ---- heads ----
    int gG = cdiv(G, 128);
    mgemm<1, 0, 0><<<dim3(gG, 2), 256, 0, stream>>>(G, 256, 256, outg, 256,
        nullptr, nullptr, nullptr, pk_lin2, lin2_b,
        fbufA, nullptr, 512, NIL);
    mgemm<1, 3, 0><<<dim3(gG, 2), 256, 0, stream>>>(G, 224, 200, mol_feats, 200,
        nullptr, nullptr, nullptr, pk_fcm0, fcm0_b,
        hm1, nullptr, 256, NIL);
    mgemm<1, 3, 0><<<dim3(gG, 2), 256, 0, stream>>>(G, 256, 256, hm1, 256,
        nullptr, nullptr, nullptr, pk_fcm1, fcm1_b,
        hm2, nullptr, 256, NIL);
    mgemm<1, 3, 0><<<dim3(gG, 2), 256, 0, stream>>>(G, 256, 256, hm2, 256,
        nullptr, nullptr, nullptr, pk_fcm2, fcm2_b,
        fbufA + 256, nullptr, 512, NIL);
    mgemm<1, 3, 0><<<dim3(gG, 4), 256, 0, stream>>>(G, 512, 512, fbufA, 512,
        nullptr, nullptr, nullptr, pk_fc0, fc0_b,
        fbufB, nullptr, 512, NIL);
    mgemm<1, 3, 0><<<dim3(gG, 4), 256, 0, stream>>>(G, 512, 512, fbufB, 512,
        nullptr, nullptr, nullptr, pk_fc1, fc1_b,
        fbufC, nullptr, 512, NIL);
    mgemm<1, 3, 0><<<dim3(gG, 4), 256, 0, stream>>>(G, 512, 512, fbufC, 512,
        nullptr, nullptr, nullptr, pk_fc2, fc2_b,
        fbufB, nullptr, 512, NIL);
    mgemm<1, 3, 0><<<dim3(gG, 1), 256, 0, stream>>>(G, 512, 512, fbufB, 512,
        nullptr, nullptr, nullptr, pk_fc3, fc3_b,
        f128, nullptr, 128, NIL);
    fc4_k<<<cdiv(G, 4), 256, 0, stream>>>(f128, fc4_w, fc4_b, out_final, G);
}

// Round 7
// 6256.571 us; speedup vs baseline: 2.6346x; 1.0593x over previous
//
#include <hip/hip_runtime.h>
#include <hip/hip_bf16.h>
#include <math.h>

// ---------------------------------------------------------------------------
// AttentiveFP forward, MI355X. Round 7: CSR gather-reduce (no atomic scatter),
// bf16 state ping-pong, sorted-batch segment sums, occupancy 4 blocks/CU.
// ---------------------------------------------------------------------------

typedef unsigned short u16;
typedef u16 u16x8 __attribute__((ext_vector_type(8)));
typedef short s16x8 __attribute__((ext_vector_type(8)));
typedef float f32x4 __attribute__((ext_vector_type(4)));

__device__ __forceinline__ float u2f(u16 u) { return __uint_as_float(((unsigned)u) << 16); }
__device__ __forceinline__ u16 f2u(float f) {
    return __builtin_bit_cast(u16, __float2bfloat16(f));  // RTN
}

#define NEGS 0.01f

__device__ __forceinline__ unsigned fkey(float f) {
    unsigned u = __float_as_uint(f);
    return (u & 0x80000000u) ? ~u : (u | 0x80000000u);
}
__device__ __forceinline__ float funkey(unsigned k) {
    return (k & 0x80000000u) ? __uint_as_float(k ^ 0x80000000u) : __uint_as_float(~k);
}
#define KEY_NEG_INF 0x007FFFFFu

static inline int cdiv(int a, int b) { return (a + b - 1) / b; }

// ---------------- utility kernels ----------------
__global__ void fill_f32(float* p, float v, size_t n) {
    size_t i = (size_t)blockIdx.x * 256 + threadIdx.x;
    if (i < n) p[i] = v;
}
__global__ void fill_u32(unsigned* p, unsigned v, int n) {
    int i = blockIdx.x * 256 + threadIdx.x;
    if (i < n) p[i] = v;
}
__global__ void copy_f2b(const float* s, u16* d, size_t n) {
    size_t i = (size_t)blockIdx.x * 256 + threadIdx.x;
    if (i < n) d[i] = f2u(s[i]);
}
__global__ void matvecT_k(const float* W, const float* a, float* v, int K, int Jout) {
    int j = blockIdx.x * 256 + threadIdx.x;
    if (j >= Jout) return;
    float s = 0.f;
    for (int k = 0; k < K; k++) s += W[(size_t)k * Jout + j] * a[k];
    v[j] = s;
}
__global__ void edge_add_lrelu(float* elog, const float* r, const int* dsti, int E) {
    int i = blockIdx.x * 256 + threadIdx.x;
    if (i < E) {
        float v = elog[i] + r[dsti[i]];
        elog[i] = v > 0.f ? v : NEGS * v;
    }
}
__global__ void pair_logit(float* elog, const float* s, const float* d,
                           const int* srci, const int* dsti, int E) {
    int i = blockIdx.x * 256 + threadIdx.x;
    if (i < E) {
        float v = s[srci[i]] + d[dsti[i]];
        elog[i] = v > 0.f ? v : NEGS * v;
    }
}
__global__ void node_logit(float* nlog, const float* asrc, const float* wg,
                           const int* batch, int N) {
    int i = blockIdx.x * 256 + threadIdx.x;
    if (i < N) {
        float v = asrc[i] + wg[batch[i]];
        nlog[i] = v > 0.f ? v : NEGS * v;
    }
}
__global__ void seg_max_k(const float* logit, const int* idx, unsigned* key, int n) {
    int i = blockIdx.x * 256 + threadIdx.x;
    if (i < n) atomicMax(&key[idx[i]], fkey(logit[i]));
}
__global__ void seg_exp_k(const float* logit, const int* idx, const unsigned* key,
                          float* ex, float* sum, int n) {
    int i = blockIdx.x * 256 + threadIdx.x;
    if (i < n) {
        float e = expf(logit[i] - funkey(key[idx[i]]));
        ex[i] = e;
        atomicAdd(&sum[idx[i]], e);
    }
}
__global__ void seg_div_k(const float* ex, const int* idx, const float* sum,
                          float* a, int n) {
    int i = blockIdx.x * 256 + threadIdx.x;
    if (i < n) a[i] = ex[i] / (sum[idx[i]] + 1e-16f);
}
__global__ void rowdot2_b(const u16* X, const float* v1, const float* v2,
                          float* o1, float* o2, int M) {
    int r = blockIdx.x * 4 + (threadIdx.x >> 6);
    int lane = threadIdx.x & 63;
    if (r >= M) return;
    const u16* row = X + (size_t)r * 256 + lane * 4;
    float p1 = 0.f, p2 = 0.f;
#pragma unroll
    for (int q = 0; q < 4; q++) {
        float xv = u2f(row[q]);
        p1 += xv * v1[lane * 4 + q];
        if (v2) p2 += xv * v2[lane * 4 + q];
    }
    for (int off = 32; off; off >>= 1) {
        p1 += __shfl_down(p1, off);
        if (v2) p2 += __shfl_down(p2, off);
    }
    if (lane == 0) {
        o1[r] = p1;
        if (v2) o2[r] = p2;
    }
}
__global__ void rowdot_f(const float* X, const float* v1, float* o1, int M) {
    int r = blockIdx.x * 4 + (threadIdx.x >> 6);
    int lane = threadIdx.x & 63;
    if (r >= M) return;
    float4 a = ((const float4*)(X + (size_t)r * 256))[lane];
    float4 b = ((const float4*)v1)[lane];
    float p1 = a.x * b.x + a.y * b.y + a.z * b.z + a.w * b.w;
    for (int off = 32; off; off >>= 1) p1 += __shfl_down(p1, off);
    if (lane == 0) o1[r] = p1;
}
__global__ void fc4_k(const float* X, const float* w, const float* b, float* out, int G) {
    int g = blockIdx.x * 4 + (threadIdx.x >> 6);
    int lane = threadIdx.x & 63;
    if (g >= G) return;
    float2 xv = ((const float2*)(X + (size_t)g * 128))[lane];
    float2 wv = ((const float2*)w)[lane];
    float p = xv.x * wv.x + xv.y * wv.y;
    for (int off = 32; off; off >>= 1) p += __shfl_down(p, off);
    if (lane == 0) out[g] = p + b[0];
}

// ---------------- CSR build (dst-grouped, order-free contiguous slots) -------
__global__ void count_dst(const int* dst, int* cnt, int E) {
    int i = blockIdx.x * 256 + threadIdx.x;
    if (i < E) atomicAdd(&cnt[dst[i]], 1);
}
__global__ void alloc_rows(const int* cnt, int* rowstart, int* cursor, int N) {
    int i = blockIdx.x * 256 + threadIdx.x;
    if (i < N) rowstart[i] = atomicAdd(cursor, cnt[i]);
}
__global__ void fill_csr(const int* dst, const int* rowstart, int* fillc,
                         int* eorder, int E) {
    int e = blockIdx.x * 256 + threadIdx.x;
    if (e >= E) return;
    int d = dst[e];
    int s = rowstart[d] + atomicAdd(&fillc[d], 1);
    eorder[s] = e;
}
// out[d,c] = sum over d's edges of a[e]*X[row,c]; MODE 0: row=src[e]; 1: row=e
template <int MODE>
__global__ void csr_reduce(const int* rowstart, const int* cnt, const int* eorder,
                           const float* a, const int* srcE, const u16* X,
                           float* out, int N) {
    int d = blockIdx.x;
    if (d >= N) return;
    int c = threadIdx.x;
    int rs = rowstart[d], k = cnt[d];
    float acc = 0.f;
    for (int s = 0; s < k; s++) {
        int e = eorder[rs + s];
        float av = a[e];
        const u16* row = (MODE == 0) ? X + (size_t)srcE[e] * 256 : X + (size_t)e * 256;
        acc += av * u2f(row[c]);
    }
    out[(size_t)d * 256 + c] = acc;
}
// ---------------- sorted-batch graph segments -------------------------------
__global__ void graph_bounds(const int* batch, int* gs, int* ge, int N) {
    int i = blockIdx.x * 256 + threadIdx.x;
    if (i >= N) return;
    int b = batch[i];
    atomicMin(&gs[b], i);
    atomicMax(&ge[b], i + 1);
}
template <bool RELU>
__global__ void seg_red(const int* gs, const int* ge, const u16* X, const float* sc,
                        float* out, int G) {
    int g = blockIdx.x;
    if (g >= G) return;
    int c = threadIdx.x;
    int s = gs[g], e = ge[g];
    float acc = 0.f;
    if (s < e)
        for (int i = s; i < e; i++) {
            float v = u2f(X[(size_t)i * 256 + c]);
            if (sc) v *= sc[i];
            acc += v;
        }
    out[(size_t)g * 256 + c] = RELU ? fmaxf(acc, 0.f) : acc;
}

// ---------------- weight pre-pack (hi||lo) into MFMA operand order ----------
__global__ void pack_w(const float* s1, const float* s2, int K1, int Ksrc,
                       int Nout, int Kp, u16* dst) {
    int idx = blockIdx.x * 256 + threadIdx.x;
    int kiters = Kp >> 5;
    int total = (Nout >> 7) * kiters * 512;
    if (idx >= total) return;
    int c = idx & 511;
    int rest = idx >> 9;
    int ki = rest % kiters, nb = rest / kiters;
    int n = (nb << 7) + (((c >> 6) & 7) << 4) + (c & 15);
    int k0 = (ki << 5) + (((c >> 4) & 3) << 3);
    u16x8 vh, vl;
#pragma unroll
    for (int j = 0; j < 8; j++) {
        int k = k0 + j;
        float f = 0.f;
        if (k < K1) f = s1[(size_t)n * K1 + k];
        else if (k < Ksrc) f = s2[(size_t)n * (Ksrc - K1) + (k - K1)];
        u16 h = f2u(f);
        vh[j] = h;
        vl[j] = f2u(f - u2f(h));
    }
    ((u16x8*)dst)[idx] = vh;
    ((u16x8*)dst)[idx + total] = vl;
}
__global__ void pack_gru_w(const float* wi, const float* wh, u16* dst) {
    int idx = blockIdx.x * 256 + threadIdx.x;
    const int total = 8 * 16 * 512;
    if (idx >= total) return;
    int c = idx & 511, rest = idx >> 9;
    int ki = rest & 15, nb = rest >> 4;
    int n = (nb << 7) + (((c >> 6) & 7) << 4) + (c & 15);
    int k0 = (ki << 5) + (((c >> 4) & 3) << 3);
    int grp = n >> 6, sub = (n >> 4) & 3, ch = grp * 16 + (n & 15);
    u16x8 vh, vl;
#pragma unroll
    for (int j = 0; j < 8; j++) {
        int k = k0 + j;
        float f;
        if (sub < 3) {
            int srow = sub * 256 + ch;
            f = (k < 256) ? wi[(size_t)srow * 256 + k]
                          : wh[(size_t)srow * 256 + (k - 256)];
        } else {
            f = (k < 256) ? 0.f : wh[(size_t)(512 + ch) * 256 + (k - 256)];
        }
        u16 h = f2u(f);
        vh[j] = h;
        vl[j] = f2u(f - u2f(h));
    }
    ((u16x8*)dst)[idx] = vh;
    ((u16x8*)dst)[idx + total] = vl;
}
__global__ void pack_gru_b(const float* bi, const float* bh, float* bp) {
    int n = blockIdx.x * 256 + threadIdx.x;
    if (n >= 1024) return;
    int grp = n >> 6, sub = (n >> 4) & 3, ch = grp * 16 + (n & 15);
    float v;
    if (sub == 0) v = bi[ch] + bh[ch];
    else if (sub == 1) v = bi[256 + ch] + bh[256 + ch];
    else if (sub == 2) v = bi[512 + ch] + bh[512 + ch];
    else v = bh[512 + ch];
    bp[n] = v;
}

// ---------------- split-bf16 loaders ----------------
struct p8 { u16x8 hi, lo; };
__device__ __forceinline__ u16x8 zero8() {
    u16x8 z;
#pragma unroll
    for (int j = 0; j < 8; j++) z[j] = 0;
    return z;
}
__device__ __forceinline__ p8 sp_zero() { p8 r; r.hi = zero8(); r.lo = zero8(); return r; }
__device__ __forceinline__ p8 sp_b(const u16* p) {
    p8 r;
    r.hi = *(const u16x8*)p;
    r.lo = zero8();
    return r;
}
__device__ __forceinline__ p8 sp_f(const float* p) {
    p8 r;
#pragma unroll
    for (int j = 0; j < 8; j++) {
        float x = p[j];
        u16 h = f2u(x);
        r.hi[j] = h;
        r.lo[j] = f2u(x - u2f(h));
    }
    return r;
}
__device__ __forceinline__ p8 sp_eluf(const float* p) {
    p8 r;
#pragma unroll
    for (int j = 0; j < 8; j++) {
        float x = p[j];
        float e = x > 0.f ? x : expm1f(x);
        u16 h = f2u(e);
        r.hi[j] = h;
        r.lo[j] = f2u(e - u2f(h));
    }
    return r;
}
// ALD: 1 f32 Af(lda) pad k>=Ksrc; 2 [xh[gidx] bf16 | edge_attr f32(16) | 0];
//      3 [elu(f32 Af) | bf16 Ab]; 4 [elu(f32 Af) | f32 X2f]
template <int ALD>
__device__ __forceinline__ p8 ldA(bool valid, int k, int Ksrc, const u16* ab,
                                  const float* af, const float* x2) {
    if (!valid) return sp_zero();
    if (ALD == 1) {
        if (k >= Ksrc) return sp_zero();
        return sp_f(af + k);
    }
    if (ALD == 2) {
        if (k < 256) return sp_b(ab + k);
        if (k < 272) return sp_f(x2 + (k - 256));
        return sp_zero();
    }
    if (ALD == 3) {
        if (k < 256) return sp_eluf(af + k);
        return sp_b(ab + (k - 256));
    }
    if (k < 256) return sp_eluf(af + k);
    return sp_f(x2 + (k - 256));
}
template <int ALD>
__device__ __forceinline__ bool lo_zero(int ki) {
    if (ALD == 2) return ki < 8;
    if (ALD == 3) return ki >= 8;
    return false;
}
template <int ACT>
__device__ __forceinline__ float actf(float v) {
    if (ACT == 1) return v > 0.f ? v : NEGS * v;
    if (ACT == 3) return v / (1.f + expf(-v));
    return v;
}

// ---------------- generic split-bf16 MFMA GEMM ----------------
// EPI: 0 f32 store; 1 bf16 store; 2 DOTV (+optional bf16 store to Cb); 3 SCAT
template <int ALD, int ACT, int EPI>
__global__ __launch_bounds__(256, 4) void mgemm(
    int M, int Kp, int Ksrc,
    const float* Af, int lda, const u16* Ab,
    const int* gidx, const float* X2f, const u16* Wp,
    const float* b1,
    float* Cf, u16* Cb, int ldc,
    const float* attv, float* dotout,
    const int* didx, const float* escale, float* scat) {
    __shared__ u16x8 lsAh[512];
    __shared__ u16x8 lsAl[512];
    __shared__ u16x8 lsWh[512];
    __shared__ u16x8 lsWl[512];
    const int t = threadIdx.x;
    const int m0 = blockIdx.x * 128;
    const int nb = blockIdx.y;
    const int kiters = Kp >> 5;
    const int r0 = ((t >> 6) << 4) | (t & 15);
    const int kq = ((t >> 4) & 3) << 3;
    const int mA[2] = {m0 + r0, m0 + r0 + 64};
    const u16* abr[2];
    const float* afr[2];
    const float* x2r[2];
    bool val[2];
#pragma unroll
    for (int h = 0; h < 2; h++) {
        int m = mA[h];
        val[h] = (m < M);
        int ms = val[h] ? m : 0;
        abr[h] = nullptr; afr[h] = nullptr; x2r[h] = nullptr;
        if (ALD == 1) {
            afr[h] = Af + (size_t)ms * lda;
        } else if (ALD == 2) {
            abr[h] = Ab + (size_t)gidx[ms] * 256;
            x2r[h] = X2f + (size_t)ms * 16;
        } else if (ALD == 3) {
            afr[h] = Af + (size_t)ms * 256;
            abr[h] = Ab + (size_t)ms * 256;
        } else {
            afr[h] = Af + (size_t)ms * 256;
            x2r[h] = X2f + (size_t)ms * 256;
        }
    }
    const int wave = t >> 6, lane = t & 63;
    const int wm = (wave >> 1) << 6, wn = (wave & 1) << 6;
    f32x4 acc[4][4];
#pragma unroll
    for (int i = 0; i < 4; i++)
#pragma unroll
        for (int j = 0; j < 4; j++) {
            acc[i][j][0] = 0.f; acc[i][j][1] = 0.f; acc[i][j][2] = 0.f; acc[i][j][3] = 0.f;
        }
    const u16x8* wh0 = (const u16x8*)Wp + ((size_t)nb * kiters << 9);
    const u16x8* wl0 = wh0 + ((size_t)gridDim.y * kiters << 9);
    for (int ki = 0; ki < kiters; ki++) {
        int kb = (ki << 5) + kq;
        p8 a0 = ldA<ALD>(val[0], kb, Ksrc, abr[0], afr[0], x2r[0]);
        p8 a1 = ldA<ALD>(val[1], kb, Ksrc, abr[1], afr[1], x2r[1]);
        lsAh[t] = a0.hi; lsAl[t] = a0.lo;
        lsAh[t + 256] = a1.hi; lsAl[t + 256] = a1.lo;
        const u16x8* wsh = wh0 + ((size_t)ki << 9);
        const u16x8* wsl = wl0 + ((size_t)ki << 9);
        lsWh[t] = wsh[t]; lsWh[t + 256] = wsh[t + 256];
        lsWl[t] = wsl[t]; lsWl[t + 256] = wsl[t + 256];
        __syncthreads();
        s16x8 ah[4], al[4], wh[4], wl[4];
#pragma unroll
        for (int f = 0; f < 4; f++) {
            int ai = ((wm >> 4) + f) * 64 + lane;
            int wi = ((wn >> 4) + f) * 64 + lane;
            ah[f] = __builtin_bit_cast(s16x8, lsAh[ai]);
            al[f] = __builtin_bit_cast(s16x8, lsAl[ai]);
            wh[f] = __builtin_bit_cast(s16x8, lsWh[wi]);
            wl[f] = __builtin_bit_cast(s16x8, lsWl[wi]);
        }
        bool skip_lh = lo_zero<ALD>(ki);
#pragma unroll
        for (int fi = 0; fi < 4; fi++)
#pragma unroll
            for (int fj = 0; fj < 4; fj++) {
                acc[fi][fj] = __builtin_amdgcn_mfma_f32_16x16x32_bf16(
                    ah[fi], wh[fj], acc[fi][fj], 0, 0, 0);
                if (!skip_lh)
                    acc[fi][fj] = __builtin_amdgcn_mfma_f32_16x16x32_bf16(
                        al[fi], wh[fj], acc[fi][fj], 0, 0, 0);
                acc[fi][fj] = __builtin_amdgcn_mfma_f32_16x16x32_bf16(
                    ah[fi], wl[fj], acc[fi][fj], 0, 0, 0);
            }
        __syncthreads();
    }
    const int col = lane & 15, quad = lane >> 4;
    const int n_base = nb * 128 + wn;
    if (EPI == 2) {
        float dp[4][4] = {};
#pragma unroll
        for (int fi = 0; fi < 4; fi++)
#pragma unroll
            for (int fj = 0; fj < 4; fj++) {
                int nn = n_base + fj * 16 + col;
                float av = attv[nn];
#pragma unroll
                for (int r = 0; r < 4; r++) {
                    float v = actf<ACT>(acc[fi][fj][r]);
                    dp[fi][r] += v * av;
                    if (Cb) {
                        int mm = m0 + wm + fi * 16 + quad * 4 + r;
                        if (mm < M) Cb[(size_t)mm * ldc + nn] = f2u(v);
                    }
                }
            }
#pragma unroll
        for (int fi = 0; fi < 4; fi++)
#pragma unroll
            for (int r = 0; r < 4; r++) {
                float p = dp[fi][r];
                p += __shfl_down(p, 8);
                p += __shfl_down(p, 4);
                p += __shfl_down(p, 2);
                p += __shfl_down(p, 1);
                int mm = m0 + wm + fi * 16 + quad * 4 + r;
                if (col == 0 && mm < M) atomicAdd(dotout + mm, p);
            }
    } else if (EPI == 3) {
#pragma unroll
        for (int fi = 0; fi < 4; fi++)
#pragma unroll
            for (int r = 0; r < 4; r++) {
                int mm = m0 + wm + fi * 16 + quad * 4 + r;
                if (mm >= M) continue;
                int d = didx[mm];
                float s = escale[mm];
                float* rowp = scat + (size_t)d * 256;
#pragma unroll
                for (int fj = 0; fj < 4; fj++) {
                    int nn = n_base + fj * 16 + col;
                    atomicAdd(rowp + nn, actf<ACT>(acc[fi][fj][r]) * s);
                }
            }
    } else {
#pragma unroll
        for (int fj = 0; fj < 4; fj++) {
            int nn = n_base + fj * 16 + col;
            float bb = b1 ? b1[nn] : 0.f;
#pragma unroll
            for (int fi = 0; fi < 4; fi++)
#pragma unroll
                for (int r = 0; r < 4; r++) {
                    int mm = m0 + wm + fi * 16 + quad * 4 + r;
                    if (mm >= M) continue;
                    float v = actf<ACT>(acc[fi][fj][r] + bb);
                    if (EPI == 1) Cb[(size_t)mm * ldc + nn] = f2u(v);
                    else Cf[(size_t)mm * ldc + nn] = v;
                }
        }
    }
}

// ---------------- fused GRU GEMM ----------------
// [elu(cbuf)|h] @ W'[1024,512]^T, cols interleaved [r|z|n|hn] per 16ch.
// HB: h_old bf16 (hb) else f32 (hf). OB: write h_new bf16 (ob) else f32 (of).
template <int ALD, bool HB, bool OB>
__global__ __launch_bounds__(256, 4) void mgemm_gru(
    int M,
    const float* Af, const u16* Ab, const float* X2f,
    const u16* Wp, const float* bp,
    const u16* hb, const float* hf, float* of, u16* ob) {
    __shared__ u16x8 lsAh[512];
    __shared__ u16x8 lsAl[512];
    __shared__ u16x8 lsWh[512];
    __shared__ u16x8 lsWl[512];
    const int t = threadIdx.x;
    const int m0 = blockIdx.x * 128;
    const int nb = blockIdx.y;  // 0..7
    const int r0 = ((t >> 6) << 4) | (t & 15);
    const int kq = ((t >> 4) & 3) << 3;
    const int mA[2] = {m0 + r0, m0 + r0 + 64};
    const u16* abr[2];
    const float* afr[2];
    const float* x2r[2];
    bool val[2];
#pragma unroll
    for (int h = 0; h < 2; h++) {
        int m = mA[h];
        val[h] = (m < M);
        int ms = val[h] ? m : 0;
        abr[h] = nullptr; x2r[h] = nullptr;
        afr[h] = Af + (size_t)ms * 256;
        if (ALD == 3) abr[h] = Ab + (size_t)ms * 256;
        else x2r[h] = X2f + (size_t)ms * 256;
    }
    const int wave = t >> 6, lane = t & 63;
    const int wm = (wave >> 1) << 6, wn = (wave & 1) << 6;
    f32x4 acc[4][4];
#pragma unroll
    for (int i = 0; i < 4; i++)
#pragma unroll
        for (int j = 0; j < 4; j++) {
            acc[i][j][0] = 0.f; acc[i][j][1] = 0.f; acc[i][j][2] = 0.f; acc[i][j][3] = 0.f;
        }
    const u16x8* wh0 = (const u16x8*)Wp + ((size_t)nb * 16 << 9);
    const u16x8* wl0 = (const u16x8*)Wp + (size_t)(8 * 16 * 512) + ((size_t)nb * 16 << 9);
    for (int ki = 0; ki < 16; ki++) {
        int kb = (ki << 5) + kq;
        p8 a0 = ldA<ALD>(val[0], kb, 512, abr[0], afr[0], x2r[0]);
        p8 a1 = ldA<ALD>(val[1], kb, 512, abr[1], afr[1], x2r[1]);
        lsAh[t] = a0.hi; lsAl[t] = a0.lo;
        lsAh[t + 256] = a1.hi; lsAl[t + 256] = a1.lo;
        const u16x8* wsh = wh0 + ((size_t)ki << 9);
        const u16x8* wsl = wl0 + ((size_t)ki << 9);
        lsWh[t] = wsh[t]; lsWh[t + 256] = wsh[t + 256];
        lsWl[t] = wsl[t]; lsWl[t + 256] = wsl[t + 256];
        __syncthreads();
        s16x8 ah[4], al[4], wh[4], wl[4];
#pragma unroll
        for (int f = 0; f < 4; f++) {
            int ai = ((wm >> 4) + f) * 64 + lane;
            int wi = ((wn >> 4) + f) * 64 + lane;
            ah[f] = __builtin_bit_cast(s16x8, lsAh[ai]);
            al[f] = __builtin_bit_cast(s16x8, lsAl[ai]);
            wh[f] = __builtin_bit_cast(s16x8, lsWh[wi]);
            wl[f] = __builtin_bit_cast(s16x8, lsWl[wi]);
        }
        bool skip_lh = lo_zero<ALD>(ki);
        bool hn_zero = (ki < 8);
#pragma unroll
        for (int fi = 0; fi < 4; fi++)
#pragma unroll
            for (int fj = 0; fj < 4; fj++) {
                if (fj == 3 && hn_zero) continue;
                acc[fi][fj] = __builtin_amdgcn_mfma_f32_16x16x32_bf16(
                    ah[fi], wh[fj], acc[fi][fj], 0, 0, 0);
                if (!skip_lh)
                    acc[fi][fj] = __builtin_amdgcn_mfma_f32_16x16x32_bf16(
                        al[fi], wh[fj], acc[fi][fj], 0, 0, 0);
                acc[fi][fj] = __builtin_amdgcn_mfma_f32_16x16x32_bf16(
                    ah[fi], wl[fj], acc[fi][fj], 0, 0, 0);
            }
        __syncthreads();
    }
    const int col = lane & 15, quad = lane >> 4;
    const int nbase = nb * 128 + wn;
    float br = bp[nbase + col];
    float bz = bp[nbase + 16 + col];
    float bn = bp[nbase + 32 + col];
    float bhn = bp[nbase + 48 + col];
    int ch = (nb * 2 + (wn >> 6)) * 16 + col;  // 0..255
#pragma unroll
    for (int fi = 0; fi < 4; fi++)
#pragma unroll
        for (int r = 0; r < 4; r++) {
            int m = m0 + wm + fi * 16 + quad * 4 + r;
            if (m >= M) continue;
            float rs = acc[fi][0][r] + br;
            float zs = acc[fi][1][r] + bz;
            float nsv = acc[fi][2][r] + bn;
            float hnv = acc[fi][3][r] + bhn;
            float rr = 1.f / (1.f + expf(-rs));
            float zz = 1.f / (1.f + expf(-zs));
            float nn = tanhf(nsv - hnv + rr * hnv);
            float ho = HB ? u2f(hb[(size_t)m * 256 + ch]) : hf[(size_t)m * 256 + ch];
            float o = fmaxf((1.f - zz) * nn + zz * ho, 0.f);
            if (OB) ob[(size_t)m * 256 + ch] = f2u(o);
            else of[(size_t)m * 256 + ch] = o;
        }
}

extern "C" void kernel_launch(void* const* d_in, const int* in_sizes, int n_in,
                              void* d_out, int out_size, void* d_ws, size_t ws_size,
                              hipStream_t stream) {
    const float* x = (const float*)d_in[0];
    const float* edge_attr = (const float*)d_in[1];
    const float* mol_feats = (const float*)d_in[2];
    const float* lin1_w = (const float*)d_in[3];
    const float* lin1_b = (const float*)d_in[4];
    const float* gate_lin1_w = (const float*)d_in[5];
    const float* gate_lin2_w = (const float*)d_in[6];
    const float* gate_att_l = (const float*)d_in[7];
    const float* gate_att_r = (const float*)d_in[8];
    const float* gate_bias = (const float*)d_in[9];
    const float* grus_wi = (const float*)d_in[10];
    const float* grus_wh = (const float*)d_in[11];
    const float* grus_bi = (const float*)d_in[12];
    const float* grus_bh = (const float*)d_in[13];
    const float* atom_w = (const float*)d_in[14];
    const float* atom_att_src = (const float*)d_in[15];
    const float* atom_att_dst = (const float*)d_in[16];
    const float* atom_bias = (const float*)d_in[17];
    const float* mol_w = (const float*)d_in[18];
    const float* mol_att_src = (const float*)d_in[19];
    const float* mol_att_dst = (const float*)d_in[20];
    const float* mol_bias = (const float*)d_in[21];
    const float* lin2_w = (const float*)d_in[22];
    const float* lin2_b = (const float*)d_in[23];
    const float* fcm0_w = (const float*)d_in[24];
    const float* fcm0_b = (const float*)d_in[25];
    const float* fcm1_w = (const float*)d_in[26];
    const float* fcm1_b = (const float*)d_in[27];
    const float* fcm2_w = (const float*)d_in[28];
    const float* fcm2_b = (const float*)d_in[29];
    const float* fc0_w = (const float*)d_in[30];
    const float* fc0_b = (const float*)d_in[31];
    const float* fc1_w = (const float*)d_in[32];
    const float* fc1_b = (const float*)d_in[33];
    const float* fc2_w = (const float*)d_in[34];
    const float* fc2_b = (const float*)d_in[35];
    const float* fc3_w = (const float*)d_in[36];
    const float* fc3_b = (const float*)d_in[37];
    const float* fc4_w = (const float*)d_in[38];
    const float* fc4_b = (const float*)d_in[39];
    const int* edge_index = (const int*)d_in[40];
    const int* batch = (const int*)d_in[41];
    float* out_final = (float*)d_out;

    const int N = in_sizes[0] / 64;
    const int E = in_sizes[1] / 16;
    const int G = in_sizes[2] / 200;
    const int* srcE = edge_index;
    const int* dstE = edge_index + E;

    // ---- workspace layout ----
    char* base = (char*)d_ws;
    size_t off = 0;
    auto alloc = [&](size_t bytes) -> char* {
        char* p = base + off;
        off += (bytes + 255) & ~(size_t)255;
        return p;
    };
    u16* xhA = (u16*)alloc((size_t)N * 256 * 2);
    float* hagg = (float*)alloc((size_t)N * 256 * 4);  // agg tgt / fallback h / heads
    float* outg = (float*)alloc((size_t)G * 256 * 4);
    float* hgrb = (float*)alloc((size_t)G * 256 * 4);
    float* elog = (float*)alloc((size_t)E * 4);
    float* eexp = (float*)alloc((size_t)E * 4);
    float* aedge = (float*)alloc((size_t)E * 4);
    unsigned* nkey = (unsigned*)alloc((size_t)N * 4);
    float* nsum = (float*)alloc((size_t)N * 4);
    float* ns1 = (float*)alloc((size_t)N * 4);
    float* ns2 = (float*)alloc((size_t)N * 4);
    unsigned* gkey = (unsigned*)alloc((size_t)G * 4);
    float* gsum = (float*)alloc((size_t)G * 4);
    float* wgb = (float*)alloc((size_t)G * 4);
    float* vbuf = (float*)alloc(1024 * 4);
    // CSR + graph bounds
    int* ecnt = (int*)alloc((size_t)N * 4);
    int* efill = (int*)alloc((size_t)N * 4);
    int* erowst = (int*)alloc((size_t)N * 4);
    int* eorder = (int*)alloc((size_t)E * 4);
    int* cursor = (int*)alloc(256);
    int* gs = (int*)alloc((size_t)G * 4);
    int* ge = (int*)alloc((size_t)G * 4);
    // packed weights (hi||lo)
    u16* pk_lin1 = (u16*)alloc(256 * 64 * 2 * 2);
    u16* pk_g1 = (u16*)alloc(256 * 288 * 2 * 2);
    u16* pk_g2 = (u16*)alloc(256 * 256 * 2 * 2);
    u16* pk_gruF[4];
    float* bp_gru[4];
    for (int l = 0; l < 4; l++) {
        pk_gruF[l] = (u16*)alloc(1024 * 512 * 2 * 2);
        bp_gru[l] = (float*)alloc(1024 * 4);
    }
    u16* pk_atom[2];
    for (int l = 0; l < 2; l++) pk_atom[l] = (u16*)alloc(256 * 256 * 2 * 2);
    u16* pk_mol = (u16*)alloc(256 * 256 * 2 * 2);
    u16* pk_lin2 = (u16*)alloc(256 * 256 * 2 * 2);
    u16* pk_fcm0 = (u16*)alloc(256 * 224 * 2 * 2);
    u16* pk_fcm1 = (u16*)alloc(256 * 256 * 2 * 2);
    u16* pk_fcm2 = (u16*)alloc(256 * 256 * 2 * 2);
    u16* pk_fc0 = (u16*)alloc(512 * 512 * 2 * 2);
    u16* pk_fc1 = (u16*)alloc(512 * 512 * 2 * 2);
    u16* pk_fc2 = (u16*)alloc(512 * 512 * 2 * 2);
    u16* pk_fc3 = (u16*)alloc(128 * 512 * 2 * 2);
    size_t fixed_core = off;
    if (fixed_core + (size_t)2 * 1024 * 1024 > ws_size) {
        fill_f32<<<cdiv(out_size, 256), 256, 0, stream>>>(out_final, (float)ws_size,
                                                          (size_t)out_size);
        return;
    }
    // optional ping-pong state buffer
    u16* xhB = nullptr;
    bool use_pp = false;
    if (ws_size - off >= (size_t)N * 512 + (size_t)2 * 1024 * 1024) {
        xhB = (u16*)alloc((size_t)N * 512);
        use_pp = true;
    }
    size_t workbytes = ws_size - off;
    char* workp = base + off;
    float* cbuf = (float*)workp;
    u16* mtmp = (u16*)workp;  // shares region with cbuf (disjoint phases)
    bool use_mtmp = workbytes >= (size_t)E * 512;
    int Mc = (int)((workbytes / 1024) & ~(size_t)127);
    if (Mc > N) Mc = N;
    if (Mc < 128) Mc = 128;
    // heads alias into hagg (dead by then)
    float* fbufA = hagg;
    float* fbufB = fbufA + (size_t)G * 512;
    float* fbufC = fbufB + (size_t)G * 512;
    float* f128 = fbufC + (size_t)G * 512;
    float* hm1 = f128 + (size_t)G * 128;
    float* hm2 = hm1 + (size_t)G * 256;

    // ---- pack all weights ----
    auto pack = [&](const float* s1, const float* s2, int K1, int Ksrc, int Nout,
                    int Kp, u16* dst) {
        int total = (Nout >> 7) * (Kp >> 5) * 512;
        pack_w<<<cdiv(total, 256), 256, 0, stream>>>(s1, s2, K1, Ksrc, Nout, Kp, dst);
    };
    pack(lin1_w, nullptr, 64, 64, 256, 64, pk_lin1);
    pack(gate_lin1_w, nullptr, 272, 272, 256, 288, pk_g1);
    pack(gate_lin2_w, nullptr, 256, 256, 256, 256, pk_g2);
    for (int l = 0; l < 4; l++) {
        pack_gru_w<<<cdiv(8 * 16 * 512, 256), 256, 0, stream>>>(
            grus_wi + (size_t)l * 768 * 256, grus_wh + (size_t)l * 768 * 256,
            pk_gruF[l]);
        pack_gru_b<<<4, 256, 0, stream>>>(grus_bi + (size_t)l * 768,
                                          grus_bh + (size_t)l * 768, bp_gru[l]);
    }
    for (int l = 0; l < 2; l++)
        pack(atom_w + (size_t)l * 256 * 256, nullptr, 256, 256, 256, 256, pk_atom[l]);
    pack(mol_w, nullptr, 256, 256, 256, 256, pk_mol);
    pack(lin2_w, nullptr, 256, 256, 256, 256, pk_lin2);
    pack(fcm0_w, nullptr, 200, 200, 256, 224, pk_fcm0);
    pack(fcm1_w, nullptr, 256, 256, 256, 256, pk_fcm1);
    pack(fcm2_w, nullptr, 256, 256, 256, 256, pk_fcm2);
    pack(fc0_w, nullptr, 512, 512, 512, 512, pk_fc0);
    pack(fc1_w, nullptr, 512, 512, 512, 512, pk_fc1);
    pack(fc2_w, nullptr, 512, 512, 512, 512, pk_fc2);
    pack(fc3_w, nullptr, 512, 512, 128, 512, pk_fc3);

    // ---- build CSR (dst) and graph bounds (batch, sorted) ----
    fill_u32<<<cdiv(N, 256), 256, 0, stream>>>((unsigned*)ecnt, 0u, N);
    fill_u32<<<cdiv(N, 256), 256, 0, stream>>>((unsigned*)efill, 0u, N);
    fill_u32<<<1, 256, 0, stream>>>((unsigned*)cursor, 0u, 1);
    count_dst<<<cdiv(E, 256), 256, 0, stream>>>(dstE, ecnt, E);
    alloc_rows<<<cdiv(N, 256), 256, 0, stream>>>(ecnt, erowst, cursor, N);
    fill_csr<<<cdiv(E, 256), 256, 0, stream>>>(dstE, erowst, efill, eorder, E);
    fill_u32<<<cdiv(G, 256), 256, 0, stream>>>((unsigned*)gs, (unsigned)N, G);
    fill_u32<<<cdiv(G, 256), 256, 0, stream>>>((unsigned*)ge, 0u, G);
    graph_bounds<<<cdiv(N, 256), 256, 0, stream>>>(batch, gs, ge, N);

#define NIL nullptr, nullptr, nullptr, nullptr, nullptr

    u16* xh_cur = xhA;
    u16* xh_nxt = xhB;

    auto node_gru = [&](int l, const u16* Wpre, const float* bpre) {
        for (int c0 = 0; c0 < N; c0 += Mc) {
            int Ms = N - c0 < Mc ? N - c0 : Mc;
            int gx = cdiv(Ms, 128);
            mgemm<1, 0, 0><<<dim3(gx, 2), 256, 0, stream>>>(Ms, 256, 256,
                hagg + (size_t)c0 * 256, 256, nullptr, nullptr, nullptr,
                Wpre, bpre, cbuf, nullptr, 256, NIL);
            if (use_pp)
                mgemm_gru<3, true, true><<<dim3(gx, 8), 256, 0, stream>>>(Ms,
                    cbuf, xh_cur + (size_t)c0 * 256, nullptr, pk_gruF[l], bp_gru[l],
                    xh_cur + (size_t)c0 * 256, nullptr, nullptr,
                    xh_nxt + (size_t)c0 * 256);
            else
                mgemm_gru<3, true, false><<<dim3(gx, 8), 256, 0, stream>>>(Ms,
                    cbuf, xh_cur + (size_t)c0 * 256, nullptr, pk_gruF[l], bp_gru[l],
                    xh_cur + (size_t)c0 * 256, nullptr,
                    hagg + (size_t)c0 * 256, nullptr);
        }
        if (use_pp) {
            u16* t2 = xh_cur; xh_cur = xh_nxt; xh_nxt = t2;
        } else {
            copy_f2b<<<(int)(((size_t)N * 256 + 255) / 256), 256, 0, stream>>>(
                hagg, xh_cur, (size_t)N * 256);
        }
    };

    // ---- xh = lrelu(x @ lin1_w^T + lin1_b) ----
    mgemm<1, 1, 1><<<dim3(cdiv(N, 128), 2), 256, 0, stream>>>(N, 64, 64,
        x, 64, nullptr, nullptr, nullptr, pk_lin1, lin1_b,
        nullptr, xh_cur, 256, NIL);

    // ---- GATEConv ----
    fill_f32<<<cdiv(E, 256), 256, 0, stream>>>(elog, 0.f, (size_t)E);
    mgemm<2, 1, 2><<<dim3(cdiv(E, 128), 2), 256, 0, stream>>>(E, 288, 272,
        nullptr, 0, xh_cur, srcE, edge_attr, pk_g1, nullptr,
        nullptr, use_mtmp ? mtmp : nullptr, 256,
        gate_att_l, elog, nullptr, nullptr, nullptr);
    rowdot2_b<<<cdiv(N, 4), 256, 0, stream>>>(xh_cur, gate_att_r, nullptr, ns1, nullptr, N);
    edge_add_lrelu<<<cdiv(E, 256), 256, 0, stream>>>(elog, ns1, dstE, E);
    fill_u32<<<cdiv(N, 256), 256, 0, stream>>>(nkey, KEY_NEG_INF, N);
    fill_f32<<<cdiv(N, 256), 256, 0, stream>>>(nsum, 0.f, (size_t)N);
    seg_max_k<<<cdiv(E, 256), 256, 0, stream>>>(elog, dstE, nkey, E);
    seg_exp_k<<<cdiv(E, 256), 256, 0, stream>>>(elog, dstE, nkey, eexp, nsum, E);
    seg_div_k<<<cdiv(E, 256), 256, 0, stream>>>(eexp, dstE, nsum, aedge, E);
    if (use_mtmp) {
        csr_reduce<1><<<N, 256, 0, stream>>>(erowst, ecnt, eorder, aedge, nullptr,
                                             mtmp, hagg, N);
    } else {
        fill_f32<<<(int)(((size_t)N * 256 + 255) / 256), 256, 0, stream>>>(
            hagg, 0.f, (size_t)N * 256);
        mgemm<2, 1, 3><<<dim3(cdiv(E, 128), 2), 256, 0, stream>>>(E, 288, 272,
            nullptr, 0, xh_cur, srcE, edge_attr, pk_g1, nullptr,
            nullptr, nullptr, 0, nullptr, nullptr, dstE, aedge, hagg);
    }
    node_gru(0, pk_g2, gate_bias);

    // ---- GATConv l=0,1 ----
    for (int l = 0; l < 2; l++) {
        const float* aw = atom_w + (size_t)l * 256 * 256;
        matvecT_k<<<1, 256, 0, stream>>>(aw, atom_att_src + (size_t)l * 256, vbuf, 256, 256);
        matvecT_k<<<1, 256, 0, stream>>>(aw, atom_att_dst + (size_t)l * 256, vbuf + 256, 256, 256);
        rowdot2_b<<<cdiv(N, 4), 256, 0, stream>>>(xh_cur, vbuf, vbuf + 256, ns1, ns2, N);
        pair_logit<<<cdiv(E, 256), 256, 0, stream>>>(elog, ns1, ns2, srcE, dstE, E);
        fill_u32<<<cdiv(N, 256), 256, 0, stream>>>(nkey, KEY_NEG_INF, N);
        fill_f32<<<cdiv(N, 256), 256, 0, stream>>>(nsum, 0.f, (size_t)N);
        seg_max_k<<<cdiv(E, 256), 256, 0, stream>>>(elog, dstE, nkey, E);
        seg_exp_k<<<cdiv(E, 256), 256, 0, stream>>>(elog, dstE, nkey, eexp, nsum, E);
        seg_div_k<<<cdiv(E, 256), 256, 0, stream>>>(eexp, dstE, nsum, aedge, E);
        csr_reduce<0><<<N, 256, 0, stream>>>(erowst, ecnt, eorder, aedge, srcE,
                                             xh_cur, hagg, N);
        node_gru(1 + l, pk_atom[l], atom_bias + (size_t)l * 256);
    }

    // ---- attentive readout ----
    seg_red<true><<<G, 256, 0, stream>>>(gs, ge, xh_cur, nullptr, outg, G);
    matvecT_k<<<1, 256, 0, stream>>>(mol_w, mol_att_dst, vbuf, 256, 256);
    matvecT_k<<<1, 256, 0, stream>>>(mol_w, mol_att_src, vbuf + 256, 256, 256);
    rowdot2_b<<<cdiv(N, 4), 256, 0, stream>>>(xh_cur, vbuf + 256, nullptr, ns1, nullptr, N);
    float* ogc = outg;
    float* ogn = hgrb;
    int McG = Mc < G ? Mc : G;
    for (int t = 0; t < 3; t++) {
        rowdot_f<<<cdiv(G, 4), 256, 0, stream>>>(ogc, vbuf, wgb, G);
        node_logit<<<cdiv(N, 256), 256, 0, stream>>>(elog, ns1, wgb, batch, N);
        fill_u32<<<cdiv(G, 256), 256, 0, stream>>>(gkey, KEY_NEG_INF, G);
        fill_f32<<<cdiv(G, 256), 256, 0, stream>>>(gsum, 0.f, (size_t)G);
        seg_max_k<<<cdiv(N, 256), 256, 0, stream>>>(elog, batch, gkey, N);
        seg_exp_k<<<cdiv(N, 256), 256, 0, stream>>>(elog, batch, gkey, eexp, gsum, N);
        seg_div_k<<<cdiv(N, 256), 256, 0, stream>>>(eexp, batch, gsum, aedge, N);
        seg_red<false><<<G, 256, 0, stream>>>(gs, ge, xh_cur, aedge, ogn, G);
        for (int c0 = 0; c0 < G; c0 += McG) {
            int Ms = G - c0 < McG ? G - c0 : McG;
            int gx = cdiv(Ms, 128);
            mgemm<1, 0, 0><<<dim3(gx, 2), 256, 0, stream>>>(Ms, 256, 256,
                ogn + (size_t)c0 * 256, 256, nullptr, nullptr, nullptr,
                pk_mol, mol_bias, cbuf, nullptr, 256, NIL);
            mgemm_gru<4, false, false><<<dim3(gx, 8), 256, 0, stream>>>(Ms,
                cbuf, nullptr, ogc + (size_t)c0 * 256, pk_gruF[3], bp_gru[3],
                nullptr, ogc + (size_t)c0 * 256, ogn + (size_t)c0 * 256, nullptr);
        }
        float* tt = ogc; ogc = ogn; ogn = tt;
    }

    // ---- heads ----
    int gG = cdiv(G, 128);
    mgemm<1, 0, 0><<<dim3(gG, 2), 256, 0, stream>>>(G, 256, 256, ogc, 256,
        nullptr, nullptr, nullptr, pk_lin2, lin2_b,
        fbufA, nullptr, 512, NIL);
    mgemm<1, 3, 0><<<dim3(gG, 2), 256, 0, stream>>>(G, 224, 200, mol_feats, 200,
        nullptr, nullptr, nullptr, pk_fcm0, fcm0_b,
        hm1, nullptr, 256, NIL);
    mgemm<1, 3, 0><<<dim3(gG, 2), 256, 0, stream>>>(G, 256, 256, hm1, 256,
        nullptr, nullptr, nullptr, pk_fcm1, fcm1_b,
        hm2, nullptr, 256, NIL);
    mgemm<1, 3, 0><<<dim3(gG, 2), 256, 0, stream>>>(G, 256, 256, hm2, 256,
        nullptr, nullptr, nullptr, pk_fcm2, fcm2_b,
        fbufA + 256, nullptr, 512, NIL);
    mgemm<1, 3, 0><<<dim3(gG, 4), 256, 0, stream>>>(G, 512, 512, fbufA, 512,
        nullptr, nullptr, nullptr, pk_fc0, fc0_b,
        fbufB, nullptr, 512, NIL);
    mgemm<1, 3, 0><<<dim3(gG, 4), 256, 0, stream>>>(G, 512, 512, fbufB, 512,
        nullptr, nullptr, nullptr, pk_fc1, fc1_b,
        fbufC, nullptr, 512, NIL);
    mgemm<1, 3, 0><<<dim3(gG, 4), 256, 0, stream>>>(G, 512, 512, fbufC, 512,
        nullptr, nullptr, nullptr, pk_fc2, fc2_b,
        fbufB, nullptr, 512, NIL);
    mgemm<1, 3, 0><<<dim3(gG, 1), 256, 0, stream>>>(G, 512, 512, fbufB, 512,
        nullptr, nullptr, nullptr, pk_fc3, fc3_b,
        f128, nullptr, 128, NIL);
    fc4_k<<<cdiv(G, 4), 256, 0, stream>>>(f128, fc4_w, fc4_b, out_final, G);
}